// Round 3
// baseline (244.970 us; speedup 1.0000x reference)
//
#include <hip/hip_runtime.h>

// Problem constants
#define NBATCH 8
#define NLQ    256
#define NLK    1024
#define NDQ    512
#define NDV    512
#define NH     128
#define NEGV   -1000000.0f
#define TANH_SCALE 2.8853900817779268f   // 2*log2(e)
#define LOG2E      1.4426950408889634f

__device__ __forceinline__ float fast_exp2(float x) {
#if __has_builtin(__builtin_amdgcn_exp2f)
  return __builtin_amdgcn_exp2f(x);
#else
  return exp2f(x);
#endif
}
__device__ __forceinline__ float fast_rcp(float x) {
#if __has_builtin(__builtin_amdgcn_rcpf)
  return __builtin_amdgcn_rcpf(x);
#else
  return 1.0f / x;
#endif
}

// ---------------------------------------------------------------------------
// Generic 64x64 fp32 tile GEMM: C[m0:m0+64, n0:n0+64] = A(MxK) @ B(KxN)
// 256 threads, 4x4 per thread, KT=32, A staged transposed. K%32==0 assumed.
// ---------------------------------------------------------------------------
__device__ __forceinline__ void gemm_tile64(const float* __restrict__ A,
                                            const float* __restrict__ Bm,
                                            float* __restrict__ C,
                                            int N, int K, int m0, int n0) {
  __shared__ float As[32][68];  // As[kk][m], padded
  __shared__ float Bs[32][68];  // Bs[kk][n], padded
  const int tid = threadIdx.x;
  const int tx = tid & 15, ty = tid >> 4;
  const int ar = tid >> 2;          // 0..63 : row within A tile
  const int ac = (tid & 3) * 8;     // kk offset for A stage
  const int brk = tid >> 3;         // 0..31 : kk row for B stage
  const int bnc = (tid & 7) * 8;    // col offset for B stage

  float acc[4][4] = {};

  for (int k0 = 0; k0 < K; k0 += 32) {
    const float4 a0 = *(const float4*)&A[(m0 + ar) * K + k0 + ac];
    const float4 a1 = *(const float4*)&A[(m0 + ar) * K + k0 + ac + 4];
    const float4 b0 = *(const float4*)&Bm[(k0 + brk) * N + n0 + bnc];
    const float4 b1 = *(const float4*)&Bm[(k0 + brk) * N + n0 + bnc + 4];
    __syncthreads();  // protect previous iteration's LDS reads
    As[ac + 0][ar] = a0.x; As[ac + 1][ar] = a0.y;
    As[ac + 2][ar] = a0.z; As[ac + 3][ar] = a0.w;
    As[ac + 4][ar] = a1.x; As[ac + 5][ar] = a1.y;
    As[ac + 6][ar] = a1.z; As[ac + 7][ar] = a1.w;
    *(float4*)&Bs[brk][bnc]     = b0;
    *(float4*)&Bs[brk][bnc + 4] = b1;
    __syncthreads();
#pragma unroll
    for (int kk = 0; kk < 32; ++kk) {
      const float4 a4 = *(const float4*)&As[kk][ty * 4];
      const float4 b4 = *(const float4*)&Bs[kk][tx * 4];
      acc[0][0] = fmaf(a4.x, b4.x, acc[0][0]);
      acc[0][1] = fmaf(a4.x, b4.y, acc[0][1]);
      acc[0][2] = fmaf(a4.x, b4.z, acc[0][2]);
      acc[0][3] = fmaf(a4.x, b4.w, acc[0][3]);
      acc[1][0] = fmaf(a4.y, b4.x, acc[1][0]);
      acc[1][1] = fmaf(a4.y, b4.y, acc[1][1]);
      acc[1][2] = fmaf(a4.y, b4.z, acc[1][2]);
      acc[1][3] = fmaf(a4.y, b4.w, acc[1][3]);
      acc[2][0] = fmaf(a4.z, b4.x, acc[2][0]);
      acc[2][1] = fmaf(a4.z, b4.y, acc[2][1]);
      acc[2][2] = fmaf(a4.z, b4.z, acc[2][2]);
      acc[2][3] = fmaf(a4.z, b4.w, acc[2][3]);
      acc[3][0] = fmaf(a4.w, b4.x, acc[3][0]);
      acc[3][1] = fmaf(a4.w, b4.y, acc[3][1]);
      acc[3][2] = fmaf(a4.w, b4.z, acc[3][2]);
      acc[3][3] = fmaf(a4.w, b4.w, acc[3][3]);
    }
  }
#pragma unroll
  for (int i = 0; i < 4; ++i) {
    float4 v = make_float4(acc[i][0], acc[i][1], acc[i][2], acc[i][3]);
    *(float4*)&C[(m0 + ty * 4 + i) * N + n0 + tx * 4] = v;
  }
}

// Fused projections: blocks [0,32) -> q = Q@Wq (M=2048), [32,160) -> k = K@Wk (M=8192)
__global__ __launch_bounds__(256)
void proj_kernel(const float* __restrict__ Q, const float* __restrict__ Kin,
                 const float* __restrict__ Wq, const float* __restrict__ Wk,
                 float* __restrict__ qp, float* __restrict__ kp) {
  int bx = blockIdx.x;
  const bool isQ = (bx < 32);
  const float* A = isQ ? Q : Kin;
  const float* W = isQ ? Wq : Wk;
  float* C = isQ ? qp : kp;
  if (!isQ) bx -= 32;
  gemm_tile64(A, W, C, NH, NDQ, bx * 64, blockIdx.y * 64);
}

// PV: out[b] = attn[b] (256x1024) @ V[b] (1024x512)
__global__ __launch_bounds__(256)
void pv_kernel(const float* __restrict__ attn, const float* __restrict__ V,
               float* __restrict__ out) {
  const int b = blockIdx.z;
  gemm_tile64(attn + b * (NLQ * NLK), V + b * (NLK * NDV), out + b * (NLQ * NDV),
              NDV, NLK, blockIdx.x * 64, blockIdx.y * 64);
}

// ---------------------------------------------------------------------------
// Scores + masked softmax, v3.
// Block = 256 threads = 4 waves. Wave w: q-row (w&1), h-half (w>>1).
// ONE ks tile [64][129] per iteration serves all 4 waves (h-halves read
// disjoint columns of the same rows). Partial scores over h-halves are
// combined via LDS aliased onto the dead ks buffer.
// score = sum_h w*tanh(q+k) = Wsum + sum_h (-2w)*rcp(1+2^((q+k)*2log2e));
// Wsum is a global constant -> cancels in softmax, dropped.
// ---------------------------------------------------------------------------
__global__ __launch_bounds__(256)
void scores_softmax_kernel(const float* __restrict__ qp, const float* __restrict__ kp,
                           const float* __restrict__ wv, const int* __restrict__ vlen,
                           float* __restrict__ attn) {
  const int b = blockIdx.y;
  const int q0 = blockIdx.x * 2;   // 2 q rows per block
  const int tid = threadIdx.x;
  const int w = tid >> 6;
  const int lane = tid & 63;
  const int qr = w & 1;            // q row within block
  const int hh = w >> 1;           // h half (0: h 0-63, 1: h 64-127)

  __shared__ float ks[64][129];    // pad 1 float: b128 bank-balanced
  __shared__ float qs[2][128];
  __shared__ float wls[128];
  float* pscomb = &ks[0][0];       // alias: 2*1024 floats, used after main loop

  // stage q rows (pre-scaled) and w_v (scaled by -2)
  qs[tid >> 7][tid & 127] = qp[(b * NLQ + q0 + (tid >> 7)) * NH + (tid & 127)] * TANH_SCALE;
  if (tid < 128) wls[tid] = -2.0f * wv[tid];
  const int VL = vlen[b];

  const float* kbase = kp + b * NLK * NH;

  float s[16];
#pragma unroll
  for (int t = 0; t < 16; ++t) {
    __syncthreads();   // previous tile consumed (and qs/wls visible at t=0)
    // stage tile t: 64 rows x 128 h = 2048 float4, 8 per thread, coalesced
#pragma unroll
    for (int j = 0; j < 8; ++j) {
      const int f = tid + 256 * j;       // 0..2047
      const int row = f >> 5;            // 0..63
      const int c4 = f & 31;             // float4 index within row
      float4 v = *(const float4*)&kbase[(t * 64 + row) * NH + c4 * 4];
      v.x *= TANH_SCALE; v.y *= TANH_SCALE; v.z *= TANH_SCALE; v.w *= TANH_SCALE;
      *(float4*)&ks[row][c4 * 4] = v;
    }
    __syncthreads();

    const float* krow = &ks[lane][hh * 64];
    const float* qrow = &qs[qr][hh * 64];
    const float* wrow = &wls[hh * 64];
    float a0 = 0.0f, a1 = 0.0f, a2 = 0.0f, a3 = 0.0f;
#pragma unroll
    for (int g = 0; g < 16; ++g) {
      const float4 kv = *(const float4*)&krow[g * 4];
      const float4 qv = *(const float4*)&qrow[g * 4];   // uniform broadcast
      const float4 wl = *(const float4*)&wrow[g * 4];   // uniform broadcast
      a0 = fmaf(wl.x, fast_rcp(1.0f + fast_exp2(qv.x + kv.x)), a0);
      a1 = fmaf(wl.y, fast_rcp(1.0f + fast_exp2(qv.y + kv.y)), a1);
      a2 = fmaf(wl.z, fast_rcp(1.0f + fast_exp2(qv.z + kv.z)), a2);
      a3 = fmaf(wl.w, fast_rcp(1.0f + fast_exp2(qv.w + kv.w)), a3);
    }
    s[t] = (a0 + a1) + (a2 + a3);
  }

  __syncthreads();                 // all ks reads done before aliasing writes
  if (hh == 1) {
#pragma unroll
    for (int t = 0; t < 16; ++t) pscomb[qr * 1024 + t * 64 + lane] = s[t];
  }
  __syncthreads();

  if (hh == 0) {
#pragma unroll
    for (int t = 0; t < 16; ++t) {
      s[t] += pscomb[qr * 1024 + t * 64 + lane];
      if (t * 64 + lane >= VL) s[t] = NEGV;
    }
    // masked softmax across 1024 = 16 regs x 64 lanes (wave-level)
    float m = s[0];
#pragma unroll
    for (int t = 1; t < 16; ++t) m = fmaxf(m, s[t]);
#pragma unroll
    for (int off = 32; off > 0; off >>= 1) m = fmaxf(m, __shfl_xor(m, off));

    float p[16];
    float sum = 0.0f;
#pragma unroll
    for (int t = 0; t < 16; ++t) {
      p[t] = fast_exp2((s[t] - m) * LOG2E);
      sum += p[t];
    }
#pragma unroll
    for (int off = 32; off > 0; off >>= 1) sum += __shfl_xor(sum, off);
    const float inv = fast_rcp(sum);

    float* arow = &attn[(b * NLQ + q0 + qr) * NLK];
#pragma unroll
    for (int t = 0; t < 16; ++t) arow[t * 64 + lane] = p[t] * inv;
  }
}

// ---------------------------------------------------------------------------
extern "C" void kernel_launch(void* const* d_in, const int* in_sizes, int n_in,
                              void* d_out, int out_size, void* d_ws, size_t ws_size,
                              hipStream_t stream) {
  const float* Q    = (const float*)d_in[0];
  const float* Kin  = (const float*)d_in[1];
  const float* V    = (const float*)d_in[2];
  const int*   vlen = (const int*)d_in[3];
  const float* Wq   = (const float*)d_in[4];
  const float* Wk   = (const float*)d_in[5];
  const float* wv   = (const float*)d_in[6];
  float* out = (float*)d_out;

  float* qp   = (float*)d_ws;                       // 2048*128
  float* kp   = qp + NBATCH * NLQ * NH;             // 8192*128
  float* attn = kp + NBATCH * NLK * NH;             // 8*256*1024

  hipLaunchKernelGGL(proj_kernel, dim3(160, 2), dim3(256), 0, stream,
                     Q, Kin, Wq, Wk, qp, kp);
  hipLaunchKernelGGL(scores_softmax_kernel, dim3(NLQ / 2, NBATCH), dim3(256), 0, stream,
                     qp, kp, wv, vlen, attn);
  hipLaunchKernelGGL(pv_kernel, dim3(NLQ / 64, NDV / 64, NBATCH), dim3(256), 0, stream,
                     attn, V, out);
}

// Round 4
// 161.374 us; speedup vs baseline: 1.5180x; 1.5180x over previous
//
#include <hip/hip_runtime.h>

// Problem constants
#define NBATCH 8
#define NLQ    256
#define NLK    1024
#define NDQ    512
#define NDV    512
#define NH     128
#define NEGV   -1000000.0f
#define TANH_SCALE 2.8853900817779268f   // 2*log2(e)
#define LOG2E      1.4426950408889634f

__device__ __forceinline__ float fast_exp2(float x) {
#if __has_builtin(__builtin_amdgcn_exp2f)
  return __builtin_amdgcn_exp2f(x);
#else
  return exp2f(x);
#endif
}
__device__ __forceinline__ float fast_rcp(float x) {
#if __has_builtin(__builtin_amdgcn_rcpf)
  return __builtin_amdgcn_rcpf(x);
#else
  return 1.0f / x;
#endif
}

// ---------------------------------------------------------------------------
// Generic 64x64 fp32 tile GEMM: C[m0:m0+64, n0:n0+64] = A(MxK) @ B(KxN)
// 256 threads, 4x4 per thread, KT=32, A staged transposed. K%32==0 assumed.
// ---------------------------------------------------------------------------
__device__ __forceinline__ void gemm_tile64(const float* __restrict__ A,
                                            const float* __restrict__ Bm,
                                            float* __restrict__ C,
                                            int N, int K, int m0, int n0) {
  __shared__ float As[32][68];  // As[kk][m], padded
  __shared__ float Bs[32][68];  // Bs[kk][n], padded
  const int tid = threadIdx.x;
  const int tx = tid & 15, ty = tid >> 4;
  const int ar = tid >> 2;          // 0..63 : row within A tile
  const int ac = (tid & 3) * 8;     // kk offset for A stage
  const int brk = tid >> 3;         // 0..31 : kk row for B stage
  const int bnc = (tid & 7) * 8;    // col offset for B stage

  float acc[4][4] = {};

  for (int k0 = 0; k0 < K; k0 += 32) {
    const float4 a0 = *(const float4*)&A[(m0 + ar) * K + k0 + ac];
    const float4 a1 = *(const float4*)&A[(m0 + ar) * K + k0 + ac + 4];
    const float4 b0 = *(const float4*)&Bm[(k0 + brk) * N + n0 + bnc];
    const float4 b1 = *(const float4*)&Bm[(k0 + brk) * N + n0 + bnc + 4];
    __syncthreads();  // protect previous iteration's LDS reads
    As[ac + 0][ar] = a0.x; As[ac + 1][ar] = a0.y;
    As[ac + 2][ar] = a0.z; As[ac + 3][ar] = a0.w;
    As[ac + 4][ar] = a1.x; As[ac + 5][ar] = a1.y;
    As[ac + 6][ar] = a1.z; As[ac + 7][ar] = a1.w;
    *(float4*)&Bs[brk][bnc]     = b0;
    *(float4*)&Bs[brk][bnc + 4] = b1;
    __syncthreads();
#pragma unroll
    for (int kk = 0; kk < 32; ++kk) {
      const float4 a4 = *(const float4*)&As[kk][ty * 4];
      const float4 b4 = *(const float4*)&Bs[kk][tx * 4];
      acc[0][0] = fmaf(a4.x, b4.x, acc[0][0]);
      acc[0][1] = fmaf(a4.x, b4.y, acc[0][1]);
      acc[0][2] = fmaf(a4.x, b4.z, acc[0][2]);
      acc[0][3] = fmaf(a4.x, b4.w, acc[0][3]);
      acc[1][0] = fmaf(a4.y, b4.x, acc[1][0]);
      acc[1][1] = fmaf(a4.y, b4.y, acc[1][1]);
      acc[1][2] = fmaf(a4.y, b4.z, acc[1][2]);
      acc[1][3] = fmaf(a4.y, b4.w, acc[1][3]);
      acc[2][0] = fmaf(a4.z, b4.x, acc[2][0]);
      acc[2][1] = fmaf(a4.z, b4.y, acc[2][1]);
      acc[2][2] = fmaf(a4.z, b4.z, acc[2][2]);
      acc[2][3] = fmaf(a4.z, b4.w, acc[2][3]);
      acc[3][0] = fmaf(a4.w, b4.x, acc[3][0]);
      acc[3][1] = fmaf(a4.w, b4.y, acc[3][1]);
      acc[3][2] = fmaf(a4.w, b4.z, acc[3][2]);
      acc[3][3] = fmaf(a4.w, b4.w, acc[3][3]);
    }
  }
#pragma unroll
  for (int i = 0; i < 4; ++i) {
    float4 v = make_float4(acc[i][0], acc[i][1], acc[i][2], acc[i][3]);
    *(float4*)&C[(m0 + ty * 4 + i) * N + n0 + tx * 4] = v;
  }
}

// Fused projections: blocks [0,32) -> q = Q@Wq (M=2048), [32,160) -> k = K@Wk (M=8192)
__global__ __launch_bounds__(256)
void proj_kernel(const float* __restrict__ Q, const float* __restrict__ Kin,
                 const float* __restrict__ Wq, const float* __restrict__ Wk,
                 float* __restrict__ qp, float* __restrict__ kp) {
  int bx = blockIdx.x;
  const bool isQ = (bx < 32);
  const float* A = isQ ? Q : Kin;
  const float* W = isQ ? Wq : Wk;
  float* C = isQ ? qp : kp;
  if (!isQ) bx -= 32;
  gemm_tile64(A, W, C, NH, NDQ, bx * 64, blockIdx.y * 64);
}

// PV: out[b] = attn[b] (256x1024) @ V[b] (1024x512)
__global__ __launch_bounds__(256)
void pv_kernel(const float* __restrict__ attn, const float* __restrict__ V,
               float* __restrict__ out) {
  const int b = blockIdx.z;
  gemm_tile64(attn + b * (NLQ * NLK), V + b * (NLK * NDV), out + b * (NLQ * NDV),
              NDV, NLK, blockIdx.x * 64, blockIdx.y * 64);
}

// ---------------------------------------------------------------------------
// Scores v4: k-vector in REGISTERS (zero per-lane LDS reads in inner loop).
// Block = 256 thr = 4 waves, all sharing one 64-key tile; wave w owns 8 q
// rows. Lane l holds key (kt*64+l)'s full h-vector in 32 float4 VGPRs,
// loaded once via coalesced HBM->LDS stage + XOR-swizzled column read
// (slot' = slot ^ (row&7): conflict-free on both write and read).
// Inner loop per 4h: 2 uniform-broadcast b128 (q, w) + 12 VALU + 8 trans.
// score = sum_h w*tanh(q+k) = Wsum + sum_h (-2w)*rcp(1+2^((q+k)*2log2e));
// Wsum constant -> cancels in softmax, dropped. Raw scores to sc (HBM).
// ---------------------------------------------------------------------------
__global__ __launch_bounds__(256)
void scores_kernel(const float* __restrict__ qp, const float* __restrict__ kp,
                   const float* __restrict__ wv, float* __restrict__ sc) {
  const int kt = blockIdx.x;     // key tile (64 keys)
  const int qg = blockIdx.y;     // q group (32 rows)
  const int b  = blockIdx.z;
  const int tid = threadIdx.x;
  const int w = tid >> 6, lane = tid & 63;

  __shared__ float ks[64 * 128];   // XOR-swizzled in float4 slots
  __shared__ float qs[32][128];
  __shared__ float wls[128];

  {
    const float* kbase = &kp[(b * NLK + kt * 64) * NH];
#pragma unroll
    for (int j = 0; j < 8; ++j) {
      const int f = tid + 256 * j;           // 0..2047
      const int row = f >> 5, slot = f & 31;
      float4 v = *(const float4*)&kbase[row * NH + slot * 4];
      v.x *= TANH_SCALE; v.y *= TANH_SCALE; v.z *= TANH_SCALE; v.w *= TANH_SCALE;
      *(float4*)&ks[row * 128 + (slot ^ (row & 7)) * 4] = v;
    }
    const float* qbase = &qp[(b * NLQ + qg * 32) * NH];
#pragma unroll
    for (int j = 0; j < 4; ++j) {
      const int f = tid + 256 * j;           // 0..1023
      const int row = f >> 5, slot = f & 31;
      float4 v = *(const float4*)&qbase[row * NH + slot * 4];
      v.x *= TANH_SCALE; v.y *= TANH_SCALE; v.z *= TANH_SCALE; v.w *= TANH_SCALE;
      *(float4*)&qs[row][slot * 4] = v;
    }
    if (tid < 128) wls[tid] = -2.0f * wv[tid];
  }
  __syncthreads();

  // k column -> registers (swizzled read: conflict-free)
  float4 kr[32];
#pragma unroll
  for (int g = 0; g < 32; ++g)
    kr[g] = *(const float4*)&ks[lane * 128 + ((g ^ (lane & 7)) * 4)];

  float* srow = &sc[(b * NLQ + qg * 32 + w * 8) * NLK + kt * 64 + lane];
  for (int qi = 0; qi < 8; ++qi) {
    const float* qrow = &qs[w * 8 + qi][0];
    float a0 = 0.0f, a1 = 0.0f, a2 = 0.0f, a3 = 0.0f;
#pragma unroll
    for (int g = 0; g < 32; ++g) {
      const float4 qv = *(const float4*)&qrow[g * 4];   // uniform broadcast
      const float4 wl = *(const float4*)&wls[g * 4];    // uniform broadcast
      const float4 kv = kr[g];
      a0 = fmaf(wl.x, fast_rcp(1.0f + fast_exp2(qv.x + kv.x)), a0);
      a1 = fmaf(wl.y, fast_rcp(1.0f + fast_exp2(qv.y + kv.y)), a1);
      a2 = fmaf(wl.z, fast_rcp(1.0f + fast_exp2(qv.z + kv.z)), a2);
      a3 = fmaf(wl.w, fast_rcp(1.0f + fast_exp2(qv.w + kv.w)), a3);
    }
    srow[qi * NLK] = (a0 + a1) + (a2 + a3);
  }
}

// ---------------------------------------------------------------------------
// Masked softmax over keys, IN PLACE on the scores buffer (becomes attn).
// Block = 4 waves; each wave owns one q-row (1024 keys = 4 float4/lane).
// ---------------------------------------------------------------------------
__global__ __launch_bounds__(256)
void softmax_kernel(float* __restrict__ sc, const int* __restrict__ vlen) {
  const int row = blockIdx.x * 4 + (threadIdx.x >> 6);  // 0..2047
  const int lane = threadIdx.x & 63;
  const int VL = vlen[row >> 8];
  float* base = &sc[row * NLK];

  float s[16];
#pragma unroll
  for (int g = 0; g < 4; ++g) {
    const int k0 = (g * 64 + lane) * 4;
    const float4 v = *(const float4*)&base[k0];
    s[g * 4 + 0] = (k0 + 0 < VL) ? v.x : NEGV;
    s[g * 4 + 1] = (k0 + 1 < VL) ? v.y : NEGV;
    s[g * 4 + 2] = (k0 + 2 < VL) ? v.z : NEGV;
    s[g * 4 + 3] = (k0 + 3 < VL) ? v.w : NEGV;
  }

  float m = s[0];
#pragma unroll
  for (int t = 1; t < 16; ++t) m = fmaxf(m, s[t]);
#pragma unroll
  for (int off = 32; off > 0; off >>= 1) m = fmaxf(m, __shfl_xor(m, off));

  float p[16];
  float sum = 0.0f;
#pragma unroll
  for (int t = 0; t < 16; ++t) {
    p[t] = fast_exp2((s[t] - m) * LOG2E);
    sum += p[t];
  }
#pragma unroll
  for (int off = 32; off > 0; off >>= 1) sum += __shfl_xor(sum, off);
  const float inv = fast_rcp(sum);

#pragma unroll
  for (int g = 0; g < 4; ++g) {
    const int k0 = (g * 64 + lane) * 4;
    float4 v;
    v.x = p[g * 4 + 0] * inv;
    v.y = p[g * 4 + 1] * inv;
    v.z = p[g * 4 + 2] * inv;
    v.w = p[g * 4 + 3] * inv;
    *(float4*)&base[k0] = v;
  }
}

// ---------------------------------------------------------------------------
extern "C" void kernel_launch(void* const* d_in, const int* in_sizes, int n_in,
                              void* d_out, int out_size, void* d_ws, size_t ws_size,
                              hipStream_t stream) {
  const float* Q    = (const float*)d_in[0];
  const float* Kin  = (const float*)d_in[1];
  const float* V    = (const float*)d_in[2];
  const int*   vlen = (const int*)d_in[3];
  const float* Wq   = (const float*)d_in[4];
  const float* Wk   = (const float*)d_in[5];
  const float* wv   = (const float*)d_in[6];
  float* out = (float*)d_out;

  float* qp   = (float*)d_ws;                       // 2048*128
  float* kp   = qp + NBATCH * NLQ * NH;             // 8192*128
  float* attn = kp + NBATCH * NLK * NH;             // 8*256*1024 (scores, then attn in place)

  hipLaunchKernelGGL(proj_kernel, dim3(160, 2), dim3(256), 0, stream,
                     Q, Kin, Wq, Wk, qp, kp);
  hipLaunchKernelGGL(scores_kernel, dim3(16, 8, NBATCH), dim3(256), 0, stream,
                     qp, kp, wv, attn);
  hipLaunchKernelGGL(softmax_kernel, dim3(NBATCH * NLQ / 4), dim3(256), 0, stream,
                     attn, vlen);
  hipLaunchKernelGGL(pv_kernel, dim3(NLQ / 64, NDV / 64, NBATCH), dim3(256), 0, stream,
                     attn, V, out);
}

// Round 5
// 140.974 us; speedup vs baseline: 1.7377x; 1.1447x over previous
//
#include <hip/hip_runtime.h>

// Problem constants
#define NBATCH 8
#define NLQ    256
#define NLK    1024
#define NDQ    512
#define NDV    512
#define NH     128
#define NEGV   -1000000.0f
#define TANH_SCALE 2.8853900817779268f   // 2*log2(e)
#define LOG2E      1.4426950408889634f

__device__ __forceinline__ float fast_exp2(float x) {
#if __has_builtin(__builtin_amdgcn_exp2f)
  return __builtin_amdgcn_exp2f(x);
#else
  return exp2f(x);
#endif
}
__device__ __forceinline__ float fast_rcp(float x) {
#if __has_builtin(__builtin_amdgcn_rcpf)
  return __builtin_amdgcn_rcpf(x);
#else
  return 1.0f / x;
#endif
}

// ---------------------------------------------------------------------------
// Generic 64x64 fp32 tile GEMM: C[m0:m0+64, n0:n0+64] = oscale * A(MxK)@B(KxN)
// 256 threads, 4x4 per thread, KT=32, A staged transposed. K%32==0 assumed.
// ---------------------------------------------------------------------------
__device__ __forceinline__ void gemm_tile64(const float* __restrict__ A,
                                            const float* __restrict__ Bm,
                                            float* __restrict__ C,
                                            int N, int K, int m0, int n0,
                                            float oscale) {
  __shared__ float As[32][68];  // As[kk][m], padded
  __shared__ float Bs[32][68];  // Bs[kk][n], padded
  const int tid = threadIdx.x;
  const int tx = tid & 15, ty = tid >> 4;
  const int ar = tid >> 2;          // 0..63 : row within A tile
  const int ac = (tid & 3) * 8;     // kk offset for A stage
  const int brk = tid >> 3;         // 0..31 : kk row for B stage
  const int bnc = (tid & 7) * 8;    // col offset for B stage

  float acc[4][4] = {};

  for (int k0 = 0; k0 < K; k0 += 32) {
    const float4 a0 = *(const float4*)&A[(m0 + ar) * K + k0 + ac];
    const float4 a1 = *(const float4*)&A[(m0 + ar) * K + k0 + ac + 4];
    const float4 b0 = *(const float4*)&Bm[(k0 + brk) * N + n0 + bnc];
    const float4 b1 = *(const float4*)&Bm[(k0 + brk) * N + n0 + bnc + 4];
    __syncthreads();  // protect previous iteration's LDS reads
    As[ac + 0][ar] = a0.x; As[ac + 1][ar] = a0.y;
    As[ac + 2][ar] = a0.z; As[ac + 3][ar] = a0.w;
    As[ac + 4][ar] = a1.x; As[ac + 5][ar] = a1.y;
    As[ac + 6][ar] = a1.z; As[ac + 7][ar] = a1.w;
    *(float4*)&Bs[brk][bnc]     = b0;
    *(float4*)&Bs[brk][bnc + 4] = b1;
    __syncthreads();
#pragma unroll
    for (int kk = 0; kk < 32; ++kk) {
      const float4 a4 = *(const float4*)&As[kk][ty * 4];
      const float4 b4 = *(const float4*)&Bs[kk][tx * 4];
      acc[0][0] = fmaf(a4.x, b4.x, acc[0][0]);
      acc[0][1] = fmaf(a4.x, b4.y, acc[0][1]);
      acc[0][2] = fmaf(a4.x, b4.z, acc[0][2]);
      acc[0][3] = fmaf(a4.x, b4.w, acc[0][3]);
      acc[1][0] = fmaf(a4.y, b4.x, acc[1][0]);
      acc[1][1] = fmaf(a4.y, b4.y, acc[1][1]);
      acc[1][2] = fmaf(a4.y, b4.z, acc[1][2]);
      acc[1][3] = fmaf(a4.y, b4.w, acc[1][3]);
      acc[2][0] = fmaf(a4.z, b4.x, acc[2][0]);
      acc[2][1] = fmaf(a4.z, b4.y, acc[2][1]);
      acc[2][2] = fmaf(a4.z, b4.z, acc[2][2]);
      acc[2][3] = fmaf(a4.z, b4.w, acc[2][3]);
      acc[3][0] = fmaf(a4.w, b4.x, acc[3][0]);
      acc[3][1] = fmaf(a4.w, b4.y, acc[3][1]);
      acc[3][2] = fmaf(a4.w, b4.z, acc[3][2]);
      acc[3][3] = fmaf(a4.w, b4.w, acc[3][3]);
    }
  }
#pragma unroll
  for (int i = 0; i < 4; ++i) {
    float4 v = make_float4(acc[i][0] * oscale, acc[i][1] * oscale,
                           acc[i][2] * oscale, acc[i][3] * oscale);
    *(float4*)&C[(m0 + ty * 4 + i) * N + n0 + tx * 4] = v;
  }
}

// Fused projections: blocks [0,32) -> q = Q@Wq (M=2048), [32,160) -> k = K@Wk (M=8192)
// Outputs are PRE-SCALED by 2*log2(e) (they only feed the scores kernel).
__global__ __launch_bounds__(256)
void proj_kernel(const float* __restrict__ Q, const float* __restrict__ Kin,
                 const float* __restrict__ Wq, const float* __restrict__ Wk,
                 float* __restrict__ qp, float* __restrict__ kp) {
  int bx = blockIdx.x;
  const bool isQ = (bx < 32);
  const float* A = isQ ? Q : Kin;
  const float* W = isQ ? Wq : Wk;
  float* C = isQ ? qp : kp;
  if (!isQ) bx -= 32;
  gemm_tile64(A, W, C, NH, NDQ, bx * 64, blockIdx.y * 64, TANH_SCALE);
}

// PV: out[b] = attn[b] (256x1024) @ V[b] (1024x512)
__global__ __launch_bounds__(256)
void pv_kernel(const float* __restrict__ attn, const float* __restrict__ V,
               float* __restrict__ out) {
  const int b = blockIdx.z;
  gemm_tile64(attn + b * (NLQ * NLK), V + b * (NLK * NDV), out + b * (NLQ * NDV),
              NDV, NLK, blockIdx.x * 64, blockIdx.y * 64, 1.0f);
}

// ---------------------------------------------------------------------------
// Scores v5: ZERO LDS. One wave per block. Lane l owns key kt*64+l, holding
// its full (pre-scaled) h-vector in 32 float4 VGPRs loaded straight from
// global (16B/lane, L2-resident). q rows and w_v are read via WAVE-UNIFORM
// addresses -> compiler emits scalar loads (K$ path, no LDS, no VMEM lanes).
// Inner loop per element: v_add(s,v) -> exp2 -> add(1+e) -> rcp -> fma(s,v).
//   score = sum_h w*tanh(q+k) = Wsum - 2*sum_h w*rcp(1+2^((q+k)*2log2e))
// Wsum constant -> cancels in softmax; -2 applied at the final store.
// ---------------------------------------------------------------------------
__global__ __launch_bounds__(64)
void scores_kernel(const float* __restrict__ qp, const float* __restrict__ kp,
                   const float* __restrict__ wv, float* __restrict__ sc) {
  const int kt = blockIdx.x;     // key tile (64 keys)
  const int qg = blockIdx.y;     // q group (8 rows)
  const int b  = blockIdx.z;
  const int lane = threadIdx.x;  // 0..63

  // k column -> registers (pre-scaled by proj)
  const float* kbase = &kp[(size_t)(b * NLK + kt * 64 + lane) * NH];
  float4 kr[32];
#pragma unroll
  for (int g = 0; g < 32; ++g) kr[g] = *(const float4*)&kbase[g * 4];

  const float* qbase = &qp[(size_t)(b * NLQ + qg * 8) * NH];

  float acc[8] = {};
#pragma unroll
  for (int g = 0; g < 32; ++g) {
    const float4 w4 = *(const float4*)&wv[g * 4];          // uniform -> s_load
    const float4 kv = kr[g];
#pragma unroll
    for (int qi = 0; qi < 8; ++qi) {
      const float4 q4 = *(const float4*)&qbase[qi * NH + g * 4];  // uniform -> s_load
      const float e0 = fast_exp2(q4.x + kv.x);
      const float e1 = fast_exp2(q4.y + kv.y);
      const float e2 = fast_exp2(q4.z + kv.z);
      const float e3 = fast_exp2(q4.w + kv.w);
      float a = acc[qi];
      a = fmaf(w4.x, fast_rcp(1.0f + e0), a);
      a = fmaf(w4.y, fast_rcp(1.0f + e1), a);
      a = fmaf(w4.z, fast_rcp(1.0f + e2), a);
      a = fmaf(w4.w, fast_rcp(1.0f + e3), a);
      acc[qi] = a;
    }
  }

#pragma unroll
  for (int qi = 0; qi < 8; ++qi)
    sc[(size_t)(b * NLQ + qg * 8 + qi) * NLK + kt * 64 + lane] = -2.0f * acc[qi];
}

// ---------------------------------------------------------------------------
// Masked softmax over keys, IN PLACE on the scores buffer (becomes attn).
// Block = 4 waves; each wave owns one q-row (1024 keys = 4 float4/lane).
// ---------------------------------------------------------------------------
__global__ __launch_bounds__(256)
void softmax_kernel(float* __restrict__ sc, const int* __restrict__ vlen) {
  const int row = blockIdx.x * 4 + (threadIdx.x >> 6);  // 0..2047
  const int lane = threadIdx.x & 63;
  const int VL = vlen[row >> 8];
  float* base = &sc[row * NLK];

  float s[16];
#pragma unroll
  for (int g = 0; g < 4; ++g) {
    const int k0 = (g * 64 + lane) * 4;
    const float4 v = *(const float4*)&base[k0];
    s[g * 4 + 0] = (k0 + 0 < VL) ? v.x : NEGV;
    s[g * 4 + 1] = (k0 + 1 < VL) ? v.y : NEGV;
    s[g * 4 + 2] = (k0 + 2 < VL) ? v.z : NEGV;
    s[g * 4 + 3] = (k0 + 3 < VL) ? v.w : NEGV;
  }

  float m = s[0];
#pragma unroll
  for (int t = 1; t < 16; ++t) m = fmaxf(m, s[t]);
#pragma unroll
  for (int off = 32; off > 0; off >>= 1) m = fmaxf(m, __shfl_xor(m, off));

  float p[16];
  float sum = 0.0f;
#pragma unroll
  for (int t = 0; t < 16; ++t) {
    p[t] = fast_exp2((s[t] - m) * LOG2E);
    sum += p[t];
  }
#pragma unroll
  for (int off = 32; off > 0; off >>= 1) sum += __shfl_xor(sum, off);
  const float inv = fast_rcp(sum);

#pragma unroll
  for (int g = 0; g < 4; ++g) {
    const int k0 = (g * 64 + lane) * 4;
    float4 v;
    v.x = p[g * 4 + 0] * inv;
    v.y = p[g * 4 + 1] * inv;
    v.z = p[g * 4 + 2] * inv;
    v.w = p[g * 4 + 3] * inv;
    *(float4*)&base[k0] = v;
  }
}

// ---------------------------------------------------------------------------
extern "C" void kernel_launch(void* const* d_in, const int* in_sizes, int n_in,
                              void* d_out, int out_size, void* d_ws, size_t ws_size,
                              hipStream_t stream) {
  const float* Q    = (const float*)d_in[0];
  const float* Kin  = (const float*)d_in[1];
  const float* V    = (const float*)d_in[2];
  const int*   vlen = (const int*)d_in[3];
  const float* Wq   = (const float*)d_in[4];
  const float* Wk   = (const float*)d_in[5];
  const float* wv   = (const float*)d_in[6];
  float* out = (float*)d_out;

  float* qp   = (float*)d_ws;                       // 2048*128 (pre-scaled)
  float* kp   = qp + NBATCH * NLQ * NH;             // 8192*128 (pre-scaled)
  float* attn = kp + NBATCH * NLK * NH;             // 8*256*1024 (scores -> attn in place)

  hipLaunchKernelGGL(proj_kernel, dim3(160, 2), dim3(256), 0, stream,
                     Q, Kin, Wq, Wk, qp, kp);
  hipLaunchKernelGGL(scores_kernel, dim3(16, 32, NBATCH), dim3(64), 0, stream,
                     qp, kp, wv, attn);
  hipLaunchKernelGGL(softmax_kernel, dim3(NBATCH * NLQ / 4), dim3(256), 0, stream,
                     attn, vlen);
  hipLaunchKernelGGL(pv_kernel, dim3(NLQ / 64, NDV / 64, NBATCH), dim3(256), 0, stream,
                     attn, V, out);
}

// Round 6
// 99.677 us; speedup vs baseline: 2.4576x; 1.4143x over previous
//
#include <hip/hip_runtime.h>

// Problem constants
#define NBATCH 8
#define NLQ    256
#define NLK    1024
#define NDQ    512
#define NDV    512
#define NH     128
#define NEGV   -1000000.0f
#define TANH_SCALE 2.8853900817779268f   // 2*log2(e)
#define LOG2E      1.4426950408889634f

using f16x8 = __attribute__((ext_vector_type(8))) _Float16;
using f16x4 = __attribute__((ext_vector_type(4))) _Float16;
using f32x4 = __attribute__((ext_vector_type(4))) float;

__device__ __forceinline__ float fast_exp2(float x) {
#if __has_builtin(__builtin_amdgcn_exp2f)
  return __builtin_amdgcn_exp2f(x);
#else
  return exp2f(x);
#endif
}
__device__ __forceinline__ float fast_rcp(float x) {
#if __has_builtin(__builtin_amdgcn_rcpf)
  return __builtin_amdgcn_rcpf(x);
#else
  return 1.0f / x;
#endif
}

// ---------------------------------------------------------------------------
// 64x64 fp32 tile GEMM for the projections; epilogue stores exp2(acc * 2log2e)
// (outputs feed ONLY the scores kernel, which needs e^{2(q+k)} = Eq*Ek).
// ---------------------------------------------------------------------------
__device__ __forceinline__ void gemm_tile64_exp(const float* __restrict__ A,
                                                const float* __restrict__ Bm,
                                                float* __restrict__ C,
                                                int N, int K, int m0, int n0) {
  __shared__ float As[32][68];  // As[kk][m], padded
  __shared__ float Bs[32][68];  // Bs[kk][n], padded
  const int tid = threadIdx.x;
  const int tx = tid & 15, ty = tid >> 4;
  const int ar = tid >> 2;          // 0..63 : row within A tile
  const int ac = (tid & 3) * 8;     // kk offset for A stage
  const int brk = tid >> 3;         // 0..31 : kk row for B stage
  const int bnc = (tid & 7) * 8;    // col offset for B stage

  float acc[4][4] = {};

  for (int k0 = 0; k0 < K; k0 += 32) {
    const float4 a0 = *(const float4*)&A[(m0 + ar) * K + k0 + ac];
    const float4 a1 = *(const float4*)&A[(m0 + ar) * K + k0 + ac + 4];
    const float4 b0 = *(const float4*)&Bm[(k0 + brk) * N + n0 + bnc];
    const float4 b1 = *(const float4*)&Bm[(k0 + brk) * N + n0 + bnc + 4];
    __syncthreads();  // protect previous iteration's LDS reads
    As[ac + 0][ar] = a0.x; As[ac + 1][ar] = a0.y;
    As[ac + 2][ar] = a0.z; As[ac + 3][ar] = a0.w;
    As[ac + 4][ar] = a1.x; As[ac + 5][ar] = a1.y;
    As[ac + 6][ar] = a1.z; As[ac + 7][ar] = a1.w;
    *(float4*)&Bs[brk][bnc]     = b0;
    *(float4*)&Bs[brk][bnc + 4] = b1;
    __syncthreads();
#pragma unroll
    for (int kk = 0; kk < 32; ++kk) {
      const float4 a4 = *(const float4*)&As[kk][ty * 4];
      const float4 b4 = *(const float4*)&Bs[kk][tx * 4];
      acc[0][0] = fmaf(a4.x, b4.x, acc[0][0]);
      acc[0][1] = fmaf(a4.x, b4.y, acc[0][1]);
      acc[0][2] = fmaf(a4.x, b4.z, acc[0][2]);
      acc[0][3] = fmaf(a4.x, b4.w, acc[0][3]);
      acc[1][0] = fmaf(a4.y, b4.x, acc[1][0]);
      acc[1][1] = fmaf(a4.y, b4.y, acc[1][1]);
      acc[1][2] = fmaf(a4.y, b4.z, acc[1][2]);
      acc[1][3] = fmaf(a4.y, b4.w, acc[1][3]);
      acc[2][0] = fmaf(a4.z, b4.x, acc[2][0]);
      acc[2][1] = fmaf(a4.z, b4.y, acc[2][1]);
      acc[2][2] = fmaf(a4.z, b4.z, acc[2][2]);
      acc[2][3] = fmaf(a4.z, b4.w, acc[2][3]);
      acc[3][0] = fmaf(a4.w, b4.x, acc[3][0]);
      acc[3][1] = fmaf(a4.w, b4.y, acc[3][1]);
      acc[3][2] = fmaf(a4.w, b4.z, acc[3][2]);
      acc[3][3] = fmaf(a4.w, b4.w, acc[3][3]);
    }
  }
#pragma unroll
  for (int i = 0; i < 4; ++i) {
    float4 v;
    v.x = fast_exp2(acc[i][0] * TANH_SCALE);
    v.y = fast_exp2(acc[i][1] * TANH_SCALE);
    v.z = fast_exp2(acc[i][2] * TANH_SCALE);
    v.w = fast_exp2(acc[i][3] * TANH_SCALE);
    *(float4*)&C[(m0 + ty * 4 + i) * N + n0 + tx * 4] = v;
  }
}

// Fused projections: blocks [0,32) -> Eq = exp2(2log2e * Q@Wq), [32,160) -> Ek
__global__ __launch_bounds__(256)
void proj_kernel(const float* __restrict__ Q, const float* __restrict__ Kin,
                 const float* __restrict__ Wq, const float* __restrict__ Wk,
                 float* __restrict__ qp, float* __restrict__ kp) {
  int bx = blockIdx.x;
  const bool isQ = (bx < 32);
  const float* A = isQ ? Q : Kin;
  const float* W = isQ ? Wq : Wk;
  float* C = isQ ? qp : kp;
  if (!isQ) bx -= 32;
  gemm_tile64_exp(A, W, C, NH, NDQ, bx * 64, blockIdx.y * 64);
}

// ---------------------------------------------------------------------------
// Scores: zero LDS, one wave per block. Lane l owns key kt*64+l: Ek vector
// (32 float4) from global (L2-resident). Eq rows + w_v via wave-uniform
// addresses -> scalar loads. Inner: e1 = fma(Eq,Ek,1); acc = fma(w, rcp(e1)).
//   score = Wsum - 2*sum_h w*rcp(1 + Eq*Ek); Wsum cancels in softmax.
// ---------------------------------------------------------------------------
__global__ __launch_bounds__(64)
void scores_kernel(const float* __restrict__ qp, const float* __restrict__ kp,
                   const float* __restrict__ wv, float* __restrict__ sc) {
  const int kt = blockIdx.x;     // key tile (64 keys)
  const int qg = blockIdx.y;     // q group (8 rows)
  const int b  = blockIdx.z;
  const int lane = threadIdx.x;  // 0..63

  const float* kbase = &kp[(size_t)(b * NLK + kt * 64 + lane) * NH];
  float4 kr[32];
#pragma unroll
  for (int g = 0; g < 32; ++g) kr[g] = *(const float4*)&kbase[g * 4];

  const float* qbase = &qp[(size_t)(b * NLQ + qg * 8) * NH];

  float acc[8] = {};
#pragma unroll
  for (int g = 0; g < 32; ++g) {
    const float4 w4 = *(const float4*)&wv[g * 4];          // uniform -> s_load
    const float4 kv = kr[g];
#pragma unroll
    for (int qi = 0; qi < 8; ++qi) {
      const float4 q4 = *(const float4*)&qbase[qi * NH + g * 4];  // uniform -> s_load
      const float e0 = fmaf(q4.x, kv.x, 1.0f);
      const float e1 = fmaf(q4.y, kv.y, 1.0f);
      const float e2 = fmaf(q4.z, kv.z, 1.0f);
      const float e3 = fmaf(q4.w, kv.w, 1.0f);
      float a = acc[qi];
      a = fmaf(w4.x, fast_rcp(e0), a);
      a = fmaf(w4.y, fast_rcp(e1), a);
      a = fmaf(w4.z, fast_rcp(e2), a);
      a = fmaf(w4.w, fast_rcp(e3), a);
      acc[qi] = a;
    }
  }

#pragma unroll
  for (int qi = 0; qi < 8; ++qi)
    sc[(size_t)(b * NLQ + qg * 8 + qi) * NLK + kt * 64 + lane] = -2.0f * acc[qi];
}

// ---------------------------------------------------------------------------
// Masked softmax over keys; reads fp32 scores, writes fp16 attn IN PLACE
// (row r's halfs [4096r, 4096r+2048) overlay row r's own floats; all reads
// complete before any store's data is ready -> safe). fp16 row stride = 2048.
// ---------------------------------------------------------------------------
__global__ __launch_bounds__(256)
void softmax_kernel(float* __restrict__ sc, const int* __restrict__ vlen) {
  const int row = blockIdx.x * 4 + (threadIdx.x >> 6);  // 0..2047
  const int lane = threadIdx.x & 63;
  const int VL = vlen[row >> 8];
  float* base = &sc[(size_t)row * NLK];

  float s[16];
#pragma unroll
  for (int g = 0; g < 4; ++g) {
    const int k0 = (g * 64 + lane) * 4;
    const float4 v = *(const float4*)&base[k0];
    s[g * 4 + 0] = (k0 + 0 < VL) ? v.x : NEGV;
    s[g * 4 + 1] = (k0 + 1 < VL) ? v.y : NEGV;
    s[g * 4 + 2] = (k0 + 2 < VL) ? v.z : NEGV;
    s[g * 4 + 3] = (k0 + 3 < VL) ? v.w : NEGV;
  }

  float m = s[0];
#pragma unroll
  for (int t = 1; t < 16; ++t) m = fmaxf(m, s[t]);
#pragma unroll
  for (int off = 32; off > 0; off >>= 1) m = fmaxf(m, __shfl_xor(m, off));

  float p[16];
  float sum = 0.0f;
#pragma unroll
  for (int t = 0; t < 16; ++t) {
    p[t] = fast_exp2((s[t] - m) * LOG2E);
    sum += p[t];
  }
#pragma unroll
  for (int off = 32; off > 0; off >>= 1) sum += __shfl_xor(sum, off);
  const float inv = fast_rcp(sum);

  _Float16* hbase = (_Float16*)base;
#pragma unroll
  for (int g = 0; g < 4; ++g) {
    const int k0 = (g * 64 + lane) * 4;
    f16x4 h;
    h[0] = (_Float16)(p[g * 4 + 0] * inv);
    h[1] = (_Float16)(p[g * 4 + 1] * inv);
    h[2] = (_Float16)(p[g * 4 + 2] * inv);
    h[3] = (_Float16)(p[g * 4 + 3] * inv);
    *(f16x4*)&hbase[k0] = h;
  }
}

// ---------------------------------------------------------------------------
// PV via fp16 MFMA: out[b] = attn[b] (256x1024 fp16, row stride 2048) @ V[b].
// Block 256 thr = 4 waves; tile M64 x N64, K-step 32. Wave w owns rows
// [w*16, w*16+16) x all 64 cols (4 MFMA frags). A: m=lane&15, k=8*(lane>>4)+j;
// B: k same, n=lane&15; C: col=lane&15, row=4*(lane>>4)+r.
// aT padded to 40 halfs/row (2-way banks); vT [n][k] with k ^= ((n>>2)&3)<<3.
// ---------------------------------------------------------------------------
__global__ __launch_bounds__(256)
void pv_mfma_kernel(const _Float16* __restrict__ attnH, const float* __restrict__ V,
                    float* __restrict__ out) {
  const int b  = blockIdx.z;
  const int m0 = blockIdx.x * 64;
  const int n0 = blockIdx.y * 64;
  const int tid = threadIdx.x;
  const int w = tid >> 6, lane = tid & 63;

  __shared__ _Float16 aT[64][40];   // [m][k]
  __shared__ _Float16 vT[64][32];   // [n][k], swizzled

  const _Float16* aBase = attnH + (size_t)(b * NLQ + m0) * 2048;
  const float*    vBase = V + (size_t)b * NLK * NDV + n0;
  float*          oBase = out + (size_t)(b * NLQ + m0) * NDV + n0;

  const int ar = tid >> 2;               // 0..63
  const int ak = (tid & 3) * 8;          // 0,8,16,24
  const int vk = tid >> 4;               // 0..15
  const int vn = (tid & 15) * 4;         // 0..60
  const int vswz = ((vn >> 2) & 3) << 3;

  const int am  = w * 16 + (lane & 15);
  const int akf = (lane >> 4) * 8;
  const int bn  = lane & 15;
  const int bks = akf ^ (((bn >> 2) & 3) << 3);

  f32x4 acc0 = {}, acc1 = {}, acc2 = {}, acc3 = {};

  for (int k0 = 0; k0 < NLK; k0 += 32) {
    __syncthreads();
    *(float4*)&aT[ar][ak] = *(const float4*)&aBase[(size_t)ar * 2048 + k0 + ak];
#pragma unroll
    for (int p = 0; p < 2; ++p) {
      const int k = p * 16 + vk;
      const float4 v = *(const float4*)&vBase[(size_t)(k0 + k) * NDV + vn];
      const int ks = k ^ vswz;
      vT[vn + 0][ks] = (_Float16)v.x;
      vT[vn + 1][ks] = (_Float16)v.y;
      vT[vn + 2][ks] = (_Float16)v.z;
      vT[vn + 3][ks] = (_Float16)v.w;
    }
    __syncthreads();

    const f16x8 af = *(const f16x8*)&aT[am][akf];
    const f16x8 bf0 = *(const f16x8*)&vT[ 0 + bn][bks];
    const f16x8 bf1 = *(const f16x8*)&vT[16 + bn][bks];
    const f16x8 bf2 = *(const f16x8*)&vT[32 + bn][bks];
    const f16x8 bf3 = *(const f16x8*)&vT[48 + bn][bks];
    acc0 = __builtin_amdgcn_mfma_f32_16x16x32_f16(af, bf0, acc0, 0, 0, 0);
    acc1 = __builtin_amdgcn_mfma_f32_16x16x32_f16(af, bf1, acc1, 0, 0, 0);
    acc2 = __builtin_amdgcn_mfma_f32_16x16x32_f16(af, bf2, acc2, 0, 0, 0);
    acc3 = __builtin_amdgcn_mfma_f32_16x16x32_f16(af, bf3, acc3, 0, 0, 0);
  }

  const int orow = w * 16 + (lane >> 4) * 4;
  const int ocol = lane & 15;
#pragma unroll
  for (int r = 0; r < 4; ++r) {
    oBase[(size_t)(orow + r) * NDV + ocol +  0] = acc0[r];
    oBase[(size_t)(orow + r) * NDV + ocol + 16] = acc1[r];
    oBase[(size_t)(orow + r) * NDV + ocol + 32] = acc2[r];
    oBase[(size_t)(orow + r) * NDV + ocol + 48] = acc3[r];
  }
}

// ---------------------------------------------------------------------------
extern "C" void kernel_launch(void* const* d_in, const int* in_sizes, int n_in,
                              void* d_out, int out_size, void* d_ws, size_t ws_size,
                              hipStream_t stream) {
  const float* Q    = (const float*)d_in[0];
  const float* Kin  = (const float*)d_in[1];
  const float* V    = (const float*)d_in[2];
  const int*   vlen = (const int*)d_in[3];
  const float* Wq   = (const float*)d_in[4];
  const float* Wk   = (const float*)d_in[5];
  const float* wv   = (const float*)d_in[6];
  float* out = (float*)d_out;

  float* qp = (float*)d_ws;                     // Eq: 2048*128
  float* kp = qp + NBATCH * NLQ * NH;           // Ek: 8192*128
  float* sc = kp + NBATCH * NLK * NH;           // scores fp32 -> attn fp16 (in place)

  hipLaunchKernelGGL(proj_kernel, dim3(160, 2), dim3(256), 0, stream,
                     Q, Kin, Wq, Wk, qp, kp);
  hipLaunchKernelGGL(scores_kernel, dim3(16, 32, NBATCH), dim3(64), 0, stream,
                     qp, kp, wv, sc);
  hipLaunchKernelGGL(softmax_kernel, dim3(NBATCH * NLQ / 4), dim3(256), 0, stream,
                     sc, vlen);
  hipLaunchKernelGGL(pv_mfma_kernel, dim3(NLQ / 64, NDV / 64, NBATCH), dim3(256), 0, stream,
                     (const _Float16*)sc, V, out);
}

// Round 7
// 97.647 us; speedup vs baseline: 2.5087x; 1.0208x over previous
//
#include <hip/hip_runtime.h>

// Problem constants
#define NBATCH 8
#define NLQ    256
#define NLK    1024
#define NDQ    512
#define NDV    512
#define NH     128
#define NEGV   -1000000.0f
#define TANH_SCALE 2.8853900817779268f   // 2*log2(e)
#define LOG2E      1.4426950408889634f

using f16x8 = __attribute__((ext_vector_type(8))) _Float16;
using f16x4 = __attribute__((ext_vector_type(4))) _Float16;
using f32x4 = __attribute__((ext_vector_type(4))) float;

__device__ __forceinline__ float fast_exp2(float x) {
#if __has_builtin(__builtin_amdgcn_exp2f)
  return __builtin_amdgcn_exp2f(x);
#else
  return exp2f(x);
#endif
}
__device__ __forceinline__ float fast_rcp(float x) {
#if __has_builtin(__builtin_amdgcn_rcpf)
  return __builtin_amdgcn_rcpf(x);
#else
  return 1.0f / x;
#endif
}

// ---------------------------------------------------------------------------
// 64x64 fp32 tile GEMM for the projections; epilogue stores exp2(acc * 2log2e)
// (outputs feed ONLY the scores kernel, which needs e^{2(q+k)} = Eq*Ek).
// ---------------------------------------------------------------------------
__device__ __forceinline__ void gemm_tile64_exp(const float* __restrict__ A,
                                                const float* __restrict__ Bm,
                                                float* __restrict__ C,
                                                int N, int K, int m0, int n0) {
  __shared__ float As[32][68];  // As[kk][m], padded
  __shared__ float Bs[32][68];  // Bs[kk][n], padded
  const int tid = threadIdx.x;
  const int tx = tid & 15, ty = tid >> 4;
  const int ar = tid >> 2;          // 0..63 : row within A tile
  const int ac = (tid & 3) * 8;     // kk offset for A stage
  const int brk = tid >> 3;         // 0..31 : kk row for B stage
  const int bnc = (tid & 7) * 8;    // col offset for B stage

  float acc[4][4] = {};

  for (int k0 = 0; k0 < K; k0 += 32) {
    const float4 a0 = *(const float4*)&A[(m0 + ar) * K + k0 + ac];
    const float4 a1 = *(const float4*)&A[(m0 + ar) * K + k0 + ac + 4];
    const float4 b0 = *(const float4*)&Bm[(k0 + brk) * N + n0 + bnc];
    const float4 b1 = *(const float4*)&Bm[(k0 + brk) * N + n0 + bnc + 4];
    __syncthreads();  // protect previous iteration's LDS reads
    As[ac + 0][ar] = a0.x; As[ac + 1][ar] = a0.y;
    As[ac + 2][ar] = a0.z; As[ac + 3][ar] = a0.w;
    As[ac + 4][ar] = a1.x; As[ac + 5][ar] = a1.y;
    As[ac + 6][ar] = a1.z; As[ac + 7][ar] = a1.w;
    *(float4*)&Bs[brk][bnc]     = b0;
    *(float4*)&Bs[brk][bnc + 4] = b1;
    __syncthreads();
#pragma unroll
    for (int kk = 0; kk < 32; ++kk) {
      const float4 a4 = *(const float4*)&As[kk][ty * 4];
      const float4 b4 = *(const float4*)&Bs[kk][tx * 4];
      acc[0][0] = fmaf(a4.x, b4.x, acc[0][0]);
      acc[0][1] = fmaf(a4.x, b4.y, acc[0][1]);
      acc[0][2] = fmaf(a4.x, b4.z, acc[0][2]);
      acc[0][3] = fmaf(a4.x, b4.w, acc[0][3]);
      acc[1][0] = fmaf(a4.y, b4.x, acc[1][0]);
      acc[1][1] = fmaf(a4.y, b4.y, acc[1][1]);
      acc[1][2] = fmaf(a4.y, b4.z, acc[1][2]);
      acc[1][3] = fmaf(a4.y, b4.w, acc[1][3]);
      acc[2][0] = fmaf(a4.z, b4.x, acc[2][0]);
      acc[2][1] = fmaf(a4.z, b4.y, acc[2][1]);
      acc[2][2] = fmaf(a4.z, b4.z, acc[2][2]);
      acc[2][3] = fmaf(a4.z, b4.w, acc[2][3]);
      acc[3][0] = fmaf(a4.w, b4.x, acc[3][0]);
      acc[3][1] = fmaf(a4.w, b4.y, acc[3][1]);
      acc[3][2] = fmaf(a4.w, b4.z, acc[3][2]);
      acc[3][3] = fmaf(a4.w, b4.w, acc[3][3]);
    }
  }
#pragma unroll
  for (int i = 0; i < 4; ++i) {
    float4 v;
    v.x = fast_exp2(acc[i][0] * TANH_SCALE);
    v.y = fast_exp2(acc[i][1] * TANH_SCALE);
    v.z = fast_exp2(acc[i][2] * TANH_SCALE);
    v.w = fast_exp2(acc[i][3] * TANH_SCALE);
    *(float4*)&C[(m0 + ty * 4 + i) * N + n0 + tx * 4] = v;
  }
}

// Fused projections: blocks [0,32) -> Eq = exp2(2log2e * Q@Wq), [32,160) -> Ek
__global__ __launch_bounds__(256)
void proj_kernel(const float* __restrict__ Q, const float* __restrict__ Kin,
                 const float* __restrict__ Wq, const float* __restrict__ Wk,
                 float* __restrict__ qp, float* __restrict__ kp) {
  int bx = blockIdx.x;
  const bool isQ = (bx < 32);
  const float* A = isQ ? Q : Kin;
  const float* W = isQ ? Wq : Wk;
  float* C = isQ ? qp : kp;
  if (!isQ) bx -= 32;
  gemm_tile64_exp(A, W, C, NH, NDQ, bx * 64, blockIdx.y * 64);
}

// ---------------------------------------------------------------------------
// Scores v7: zero LDS, 256-thr blocks (4 waves, each wave its own key tile).
// Grid (4,64,8) = 2048 blocks -> 8 blocks/CU = 32 waves/CU (full occupancy).
// Lane l owns key kt*64+l: Ek streamed from global (L2-resident) per g.
// Eq rows (4 per wave) + w_v via wave-uniform addresses -> scalar loads.
// Inner: e = fma(Eq,Ek,1); acc = fma(w, rcp(e)).
//   score = Wsum - 2*sum_h w*rcp(1 + Eq*Ek); Wsum cancels in softmax.
// ---------------------------------------------------------------------------
__global__ __launch_bounds__(256)
void scores_kernel(const float* __restrict__ qp, const float* __restrict__ kp,
                   const float* __restrict__ wv, float* __restrict__ sc) {
  const int w = threadIdx.x >> 6;
  const int lane = threadIdx.x & 63;
  const int kt = blockIdx.x * 4 + w;   // key tile (64 keys)
  const int qg = blockIdx.y;           // q group (4 rows)
  const int b  = blockIdx.z;

  const float* kbase = &kp[(size_t)(b * NLK + kt * 64 + lane) * NH];
  const float* qbase = &qp[(size_t)(b * NLQ + qg * 4) * NH];

  float acc[4] = {};
#pragma unroll
  for (int g = 0; g < 32; ++g) {
    const float4 w4 = *(const float4*)&wv[g * 4];          // uniform -> s_load
    const float4 kv = *(const float4*)&kbase[g * 4];       // per-lane, L2
#pragma unroll
    for (int qi = 0; qi < 4; ++qi) {
      const float4 q4 = *(const float4*)&qbase[qi * NH + g * 4];  // uniform -> s_load
      const float e0 = fmaf(q4.x, kv.x, 1.0f);
      const float e1 = fmaf(q4.y, kv.y, 1.0f);
      const float e2 = fmaf(q4.z, kv.z, 1.0f);
      const float e3 = fmaf(q4.w, kv.w, 1.0f);
      float a = acc[qi];
      a = fmaf(w4.x, fast_rcp(e0), a);
      a = fmaf(w4.y, fast_rcp(e1), a);
      a = fmaf(w4.z, fast_rcp(e2), a);
      a = fmaf(w4.w, fast_rcp(e3), a);
      acc[qi] = a;
    }
  }

#pragma unroll
  for (int qi = 0; qi < 4; ++qi)
    sc[(size_t)(b * NLQ + qg * 4 + qi) * NLK + kt * 64 + lane] = -2.0f * acc[qi];
}

// ---------------------------------------------------------------------------
// Masked softmax over keys; reads fp32 scores, writes fp16 attn IN PLACE
// (row r's halfs [4096r, 4096r+2048) overlay row r's own floats; all reads
// complete before any store's data is ready -> safe). fp16 row stride = 2048.
// ---------------------------------------------------------------------------
__global__ __launch_bounds__(256)
void softmax_kernel(float* __restrict__ sc, const int* __restrict__ vlen) {
  const int row = blockIdx.x * 4 + (threadIdx.x >> 6);  // 0..2047
  const int lane = threadIdx.x & 63;
  const int VL = vlen[row >> 8];
  float* base = &sc[(size_t)row * NLK];

  float s[16];
#pragma unroll
  for (int g = 0; g < 4; ++g) {
    const int k0 = (g * 64 + lane) * 4;
    const float4 v = *(const float4*)&base[k0];
    s[g * 4 + 0] = (k0 + 0 < VL) ? v.x : NEGV;
    s[g * 4 + 1] = (k0 + 1 < VL) ? v.y : NEGV;
    s[g * 4 + 2] = (k0 + 2 < VL) ? v.z : NEGV;
    s[g * 4 + 3] = (k0 + 3 < VL) ? v.w : NEGV;
  }

  float m = s[0];
#pragma unroll
  for (int t = 1; t < 16; ++t) m = fmaxf(m, s[t]);
#pragma unroll
  for (int off = 32; off > 0; off >>= 1) m = fmaxf(m, __shfl_xor(m, off));

  float p[16];
  float sum = 0.0f;
#pragma unroll
  for (int t = 0; t < 16; ++t) {
    p[t] = fast_exp2((s[t] - m) * LOG2E);
    sum += p[t];
  }
#pragma unroll
  for (int off = 32; off > 0; off >>= 1) sum += __shfl_xor(sum, off);
  const float inv = fast_rcp(sum);

  _Float16* hbase = (_Float16*)base;
#pragma unroll
  for (int g = 0; g < 4; ++g) {
    const int k0 = (g * 64 + lane) * 4;
    f16x4 h;
    h[0] = (_Float16)(p[g * 4 + 0] * inv);
    h[1] = (_Float16)(p[g * 4 + 1] * inv);
    h[2] = (_Float16)(p[g * 4 + 2] * inv);
    h[3] = (_Float16)(p[g * 4 + 3] * inv);
    *(f16x4*)&hbase[k0] = h;
  }
}

// ---------------------------------------------------------------------------
// PV via fp16 MFMA: out[b] = attn[b] (256x1024 fp16, row stride 2048) @ V[b].
// Block 256 thr = 4 waves; tile M64 x N64, K-step 32. Wave w owns rows
// [w*16, w*16+16) x all 64 cols (4 MFMA frags). A: m=lane&15, k=8*(lane>>4)+j;
// B: k same, n=lane&15; C: col=lane&15, row=4*(lane>>4)+r.
// aT padded to 40 halfs/row; vT [n][k] with k ^= ((n>>2)&3)<<3.
// Register prefetch: next tile's global loads issue BEFORE current MFMAs,
// so HBM/L2 latency hides under compute (T14-style issue-early/write-late).
// ---------------------------------------------------------------------------
__global__ __launch_bounds__(256)
void pv_mfma_kernel(const _Float16* __restrict__ attnH, const float* __restrict__ V,
                    float* __restrict__ out) {
  const int b  = blockIdx.z;
  const int m0 = blockIdx.x * 64;
  const int n0 = blockIdx.y * 64;
  const int tid = threadIdx.x;
  const int w = tid >> 6, lane = tid & 63;

  __shared__ _Float16 aT[64][40];   // [m][k]
  __shared__ _Float16 vT[64][32];   // [n][k], swizzled

  const _Float16* aBase = attnH + (size_t)(b * NLQ + m0) * 2048;
  const float*    vBase = V + (size_t)b * NLK * NDV + n0;
  float*          oBase = out + (size_t)(b * NLQ + m0) * NDV + n0;

  const int ar = tid >> 2;               // 0..63
  const int ak = (tid & 3) * 8;          // 0,8,16,24
  const int vk = tid >> 4;               // 0..15
  const int vn = (tid & 15) * 4;         // 0..60
  const int vswz = ((vn >> 2) & 3) << 3;

  const int am  = w * 16 + (lane & 15);
  const int akf = (lane >> 4) * 8;
  const int bn  = lane & 15;
  const int bks = akf ^ (((bn >> 2) & 3) << 3);

  f32x4 acc0 = {}, acc1 = {}, acc2 = {}, acc3 = {};

  // prologue: prefetch tile 0 into registers
  float4 aReg = *(const float4*)&aBase[(size_t)ar * 2048 + ak];
  float4 vReg0 = *(const float4*)&vBase[(size_t)(vk) * NDV + vn];
  float4 vReg1 = *(const float4*)&vBase[(size_t)(16 + vk) * NDV + vn];

  for (int k0 = 0; k0 < NLK; k0 += 32) {
    __syncthreads();   // previous tile's LDS reads complete
    *(float4*)&aT[ar][ak] = aReg;
    {
      const int ks0 = vk ^ vswz;
      vT[vn + 0][ks0] = (_Float16)vReg0.x;
      vT[vn + 1][ks0] = (_Float16)vReg0.y;
      vT[vn + 2][ks0] = (_Float16)vReg0.z;
      vT[vn + 3][ks0] = (_Float16)vReg0.w;
      const int ks1 = (16 + vk) ^ vswz;
      vT[vn + 0][ks1] = (_Float16)vReg1.x;
      vT[vn + 1][ks1] = (_Float16)vReg1.y;
      vT[vn + 2][ks1] = (_Float16)vReg1.z;
      vT[vn + 3][ks1] = (_Float16)vReg1.w;
    }
    __syncthreads();

    // prefetch NEXT tile while current MFMAs run
    if (k0 + 32 < NLK) {
      aReg = *(const float4*)&aBase[(size_t)ar * 2048 + k0 + 32 + ak];
      vReg0 = *(const float4*)&vBase[(size_t)(k0 + 32 + vk) * NDV + vn];
      vReg1 = *(const float4*)&vBase[(size_t)(k0 + 48 + vk) * NDV + vn];
    }

    const f16x8 af = *(const f16x8*)&aT[am][akf];
    const f16x8 bf0 = *(const f16x8*)&vT[ 0 + bn][bks];
    const f16x8 bf1 = *(const f16x8*)&vT[16 + bn][bks];
    const f16x8 bf2 = *(const f16x8*)&vT[32 + bn][bks];
    const f16x8 bf3 = *(const f16x8*)&vT[48 + bn][bks];
    acc0 = __builtin_amdgcn_mfma_f32_16x16x32_f16(af, bf0, acc0, 0, 0, 0);
    acc1 = __builtin_amdgcn_mfma_f32_16x16x32_f16(af, bf1, acc1, 0, 0, 0);
    acc2 = __builtin_amdgcn_mfma_f32_16x16x32_f16(af, bf2, acc2, 0, 0, 0);
    acc3 = __builtin_amdgcn_mfma_f32_16x16x32_f16(af, bf3, acc3, 0, 0, 0);
  }

  const int orow = w * 16 + (lane >> 4) * 4;
  const int ocol = lane & 15;
#pragma unroll
  for (int r = 0; r < 4; ++r) {
    oBase[(size_t)(orow + r) * NDV + ocol +  0] = acc0[r];
    oBase[(size_t)(orow + r) * NDV + ocol + 16] = acc1[r];
    oBase[(size_t)(orow + r) * NDV + ocol + 32] = acc2[r];
    oBase[(size_t)(orow + r) * NDV + ocol + 48] = acc3[r];
  }
}

// ---------------------------------------------------------------------------
extern "C" void kernel_launch(void* const* d_in, const int* in_sizes, int n_in,
                              void* d_out, int out_size, void* d_ws, size_t ws_size,
                              hipStream_t stream) {
  const float* Q    = (const float*)d_in[0];
  const float* Kin  = (const float*)d_in[1];
  const float* V    = (const float*)d_in[2];
  const int*   vlen = (const int*)d_in[3];
  const float* Wq   = (const float*)d_in[4];
  const float* Wk   = (const float*)d_in[5];
  const float* wv   = (const float*)d_in[6];
  float* out = (float*)d_out;

  float* qp = (float*)d_ws;                     // Eq: 2048*128
  float* kp = qp + NBATCH * NLQ * NH;           // Ek: 8192*128
  float* sc = kp + NBATCH * NLK * NH;           // scores fp32 -> attn fp16 (in place)

  hipLaunchKernelGGL(proj_kernel, dim3(160, 2), dim3(256), 0, stream,
                     Q, Kin, Wq, Wk, qp, kp);
  hipLaunchKernelGGL(scores_kernel, dim3(4, 64, NBATCH), dim3(256), 0, stream,
                     qp, kp, wv, sc);
  hipLaunchKernelGGL(softmax_kernel, dim3(NBATCH * NLQ / 4), dim3(256), 0, stream,
                     sc, vlen);
  hipLaunchKernelGGL(pv_mfma_kernel, dim3(NLQ / 64, NDV / 64, NBATCH), dim3(256), 0, stream,
                     (const _Float16*)sc, V, out);
}

// Round 8
// 91.783 us; speedup vs baseline: 2.6690x; 1.0639x over previous
//
#include <hip/hip_runtime.h>

// Problem constants
#define NBATCH 8
#define NLQ    256
#define NLK    1024
#define NDQ    512
#define NDV    512
#define NH     128
#define NEGV   -1000000.0f
#define TANH_SCALE 2.8853900817779268f   // 2*log2(e)
#define LOG2E      1.4426950408889634f

using f16x8 = __attribute__((ext_vector_type(8))) _Float16;
using f16x4 = __attribute__((ext_vector_type(4))) _Float16;
using f32x4 = __attribute__((ext_vector_type(4))) float;

__device__ __forceinline__ float fast_exp2(float x) {
#if __has_builtin(__builtin_amdgcn_exp2f)
  return __builtin_amdgcn_exp2f(x);
#else
  return exp2f(x);
#endif
}
__device__ __forceinline__ float fast_rcp(float x) {
#if __has_builtin(__builtin_amdgcn_rcpf)
  return __builtin_amdgcn_rcpf(x);
#else
  return 1.0f / x;
#endif
}

// ---------------------------------------------------------------------------
// 64x64 fp32 tile GEMM for the projections; epilogue stores exp2(acc*2log2e).
// transK=false: row-major C[m][n] (Eq).  transK=true: C is EkT[b][h][key]
// (batch = m>>10, key = m&1023): scatter stores, amortized by the GEMM.
// ---------------------------------------------------------------------------
__device__ __forceinline__ void gemm_tile64_exp(const float* __restrict__ A,
                                                const float* __restrict__ Bm,
                                                float* __restrict__ C,
                                                int N, int K, int m0, int n0,
                                                bool transK) {
  __shared__ float As[32][68];  // As[kk][m], padded
  __shared__ float Bs[32][68];  // Bs[kk][n], padded
  const int tid = threadIdx.x;
  const int tx = tid & 15, ty = tid >> 4;
  const int ar = tid >> 2;          // 0..63 : row within A tile
  const int ac = (tid & 3) * 8;     // kk offset for A stage
  const int brk = tid >> 3;         // 0..31 : kk row for B stage
  const int bnc = (tid & 7) * 8;    // col offset for B stage

  float acc[4][4] = {};

  for (int k0 = 0; k0 < K; k0 += 32) {
    const float4 a0 = *(const float4*)&A[(m0 + ar) * K + k0 + ac];
    const float4 a1 = *(const float4*)&A[(m0 + ar) * K + k0 + ac + 4];
    const float4 b0 = *(const float4*)&Bm[(k0 + brk) * N + n0 + bnc];
    const float4 b1 = *(const float4*)&Bm[(k0 + brk) * N + n0 + bnc + 4];
    __syncthreads();  // protect previous iteration's LDS reads
    As[ac + 0][ar] = a0.x; As[ac + 1][ar] = a0.y;
    As[ac + 2][ar] = a0.z; As[ac + 3][ar] = a0.w;
    As[ac + 4][ar] = a1.x; As[ac + 5][ar] = a1.y;
    As[ac + 6][ar] = a1.z; As[ac + 7][ar] = a1.w;
    *(float4*)&Bs[brk][bnc]     = b0;
    *(float4*)&Bs[brk][bnc + 4] = b1;
    __syncthreads();
#pragma unroll
    for (int kk = 0; kk < 32; ++kk) {
      const float4 a4 = *(const float4*)&As[kk][ty * 4];
      const float4 b4 = *(const float4*)&Bs[kk][tx * 4];
      acc[0][0] = fmaf(a4.x, b4.x, acc[0][0]);
      acc[0][1] = fmaf(a4.x, b4.y, acc[0][1]);
      acc[0][2] = fmaf(a4.x, b4.z, acc[0][2]);
      acc[0][3] = fmaf(a4.x, b4.w, acc[0][3]);
      acc[1][0] = fmaf(a4.y, b4.x, acc[1][0]);
      acc[1][1] = fmaf(a4.y, b4.y, acc[1][1]);
      acc[1][2] = fmaf(a4.y, b4.z, acc[1][2]);
      acc[1][3] = fmaf(a4.y, b4.w, acc[1][3]);
      acc[2][0] = fmaf(a4.z, b4.x, acc[2][0]);
      acc[2][1] = fmaf(a4.z, b4.y, acc[2][1]);
      acc[2][2] = fmaf(a4.z, b4.z, acc[2][2]);
      acc[2][3] = fmaf(a4.z, b4.w, acc[2][3]);
      acc[3][0] = fmaf(a4.w, b4.x, acc[3][0]);
      acc[3][1] = fmaf(a4.w, b4.y, acc[3][1]);
      acc[3][2] = fmaf(a4.w, b4.z, acc[3][2]);
      acc[3][3] = fmaf(a4.w, b4.w, acc[3][3]);
    }
  }

  if (!transK) {
#pragma unroll
    for (int i = 0; i < 4; ++i) {
      float4 v;
      v.x = fast_exp2(acc[i][0] * TANH_SCALE);
      v.y = fast_exp2(acc[i][1] * TANH_SCALE);
      v.z = fast_exp2(acc[i][2] * TANH_SCALE);
      v.w = fast_exp2(acc[i][3] * TANH_SCALE);
      *(float4*)&C[(m0 + ty * 4 + i) * N + n0 + tx * 4] = v;
    }
  } else {
    const int bb = m0 >> 10;           // batch (64 | 1024)
#pragma unroll
    for (int i = 0; i < 4; ++i) {
      const int key = (m0 + ty * 4 + i) & 1023;
#pragma unroll
      for (int j = 0; j < 4; ++j) {
        const int h = n0 + tx * 4 + j;
        C[((size_t)bb * NH + h) * NLK + key] = fast_exp2(acc[i][j] * TANH_SCALE);
      }
    }
  }
}

// Fused projections: blocks [0,32) -> Eq = exp2(2log2e*Q@Wq) row-major,
// blocks [32,160) -> EkT = exp2(2log2e*K@Wk) stored [b][h][key].
__global__ __launch_bounds__(256)
void proj_kernel(const float* __restrict__ Q, const float* __restrict__ Kin,
                 const float* __restrict__ Wq, const float* __restrict__ Wk,
                 float* __restrict__ qp, float* __restrict__ ekT) {
  int bx = blockIdx.x;
  const bool isQ = (bx < 32);
  if (isQ) {
    gemm_tile64_exp(Q, Wq, qp, NH, NDQ, bx * 64, blockIdx.y * 64, false);
  } else {
    gemm_tile64_exp(Kin, Wk, ekT, NH, NDQ, (bx - 32) * 64, blockIdx.y * 64, true);
  }
}

// ---------------------------------------------------------------------------
// Scores v8: COALESCED k. EkT[b][h][key]: lane owns keys key0=seg*128+2*lane
// (float2 loads -> consecutive lanes, consecutive addresses, 8 CLs/wave-load
// instead of 64). Eq rows + w_v via wave-uniform addresses -> scalar loads.
// Per wave: 128 keys x 4 q rows. Grid (2,64,8) x 4 waves = 4096 waves.
//   score = Wsum - 2*sum_h w*rcp(1 + Eq*Ek); Wsum cancels in softmax.
// ---------------------------------------------------------------------------
__global__ __launch_bounds__(256)
void scores_kernel(const float* __restrict__ qp, const float* __restrict__ ekT,
                   const float* __restrict__ wv, float* __restrict__ sc) {
  const int w = threadIdx.x >> 6;
  const int lane = threadIdx.x & 63;
  const int seg = blockIdx.x * 4 + w;   // key segment (128 keys)
  const int qg  = blockIdx.y;           // q group (4 rows)
  const int b   = blockIdx.z;
  const int key0 = seg * 128 + lane * 2;

  const float* kcol  = &ekT[(size_t)b * NH * NLK + key0];       // + h*NLK
  const float* qbase = &qp[(size_t)(b * NLQ + qg * 4) * NH];

  float2 acc[4] = {};
#pragma unroll 8
  for (int g = 0; g < 32; ++g) {
    const float4 w4 = *(const float4*)&wv[g * 4];               // uniform
    float4 q4[4];
#pragma unroll
    for (int qi = 0; qi < 4; ++qi)
      q4[qi] = *(const float4*)&qbase[qi * NH + g * 4];         // uniform
#pragma unroll
    for (int hh = 0; hh < 4; ++hh) {
      const float2 kv = *(const float2*)&kcol[(size_t)(g * 4 + hh) * NLK];
      const float wl = (hh == 0) ? w4.x : (hh == 1) ? w4.y : (hh == 2) ? w4.z : w4.w;
#pragma unroll
      for (int qi = 0; qi < 4; ++qi) {
        const float qs = (hh == 0) ? q4[qi].x : (hh == 1) ? q4[qi].y
                       : (hh == 2) ? q4[qi].z : q4[qi].w;
        acc[qi].x = fmaf(wl, fast_rcp(fmaf(qs, kv.x, 1.0f)), acc[qi].x);
        acc[qi].y = fmaf(wl, fast_rcp(fmaf(qs, kv.y, 1.0f)), acc[qi].y);
      }
    }
  }

#pragma unroll
  for (int qi = 0; qi < 4; ++qi) {
    float2 o;
    o.x = -2.0f * acc[qi].x;
    o.y = -2.0f * acc[qi].y;
    *(float2*)&sc[(size_t)(b * NLQ + qg * 4 + qi) * NLK + key0] = o;
  }
}

// ---------------------------------------------------------------------------
// Masked softmax over keys; reads fp32 scores, writes fp16 attn IN PLACE
// (row r's halfs [4096r, 4096r+2048) overlay row r's own floats; all reads
// complete before any store's data is ready -> safe). fp16 row stride = 2048.
// ---------------------------------------------------------------------------
__global__ __launch_bounds__(256)
void softmax_kernel(float* __restrict__ sc, const int* __restrict__ vlen) {
  const int row = blockIdx.x * 4 + (threadIdx.x >> 6);  // 0..2047
  const int lane = threadIdx.x & 63;
  const int VL = vlen[row >> 8];
  float* base = &sc[(size_t)row * NLK];

  float s[16];
#pragma unroll
  for (int g = 0; g < 4; ++g) {
    const int k0 = (g * 64 + lane) * 4;
    const float4 v = *(const float4*)&base[k0];
    s[g * 4 + 0] = (k0 + 0 < VL) ? v.x : NEGV;
    s[g * 4 + 1] = (k0 + 1 < VL) ? v.y : NEGV;
    s[g * 4 + 2] = (k0 + 2 < VL) ? v.z : NEGV;
    s[g * 4 + 3] = (k0 + 3 < VL) ? v.w : NEGV;
  }

  float m = s[0];
#pragma unroll
  for (int t = 1; t < 16; ++t) m = fmaxf(m, s[t]);
#pragma unroll
  for (int off = 32; off > 0; off >>= 1) m = fmaxf(m, __shfl_xor(m, off));

  float p[16];
  float sum = 0.0f;
#pragma unroll
  for (int t = 0; t < 16; ++t) {
    p[t] = fast_exp2((s[t] - m) * LOG2E);
    sum += p[t];
  }
#pragma unroll
  for (int off = 32; off > 0; off >>= 1) sum += __shfl_xor(sum, off);
  const float inv = fast_rcp(sum);

  _Float16* hbase = (_Float16*)base;
#pragma unroll
  for (int g = 0; g < 4; ++g) {
    const int k0 = (g * 64 + lane) * 4;
    f16x4 h;
    h[0] = (_Float16)(p[g * 4 + 0] * inv);
    h[1] = (_Float16)(p[g * 4 + 1] * inv);
    h[2] = (_Float16)(p[g * 4 + 2] * inv);
    h[3] = (_Float16)(p[g * 4 + 3] * inv);
    *(f16x4*)&hbase[k0] = h;
  }
}

// ---------------------------------------------------------------------------
// PV via fp16 MFMA: out[b] = attn[b] (256x1024 fp16, row stride 2048) @ V[b].
// Block 256 thr = 4 waves; tile M64 x N64, K-step 32. A: m=lane&15,
// k=8*(lane>>4)+j; B mirrored; C: col=lane&15, row=4*(lane>>4)+r.
// aT padded to 40 halfs/row; vT [n][k] with k ^= ((n>>2)&3)<<3.
// Register prefetch: next tile's global loads issue BEFORE current MFMAs.
// ---------------------------------------------------------------------------
__global__ __launch_bounds__(256)
void pv_mfma_kernel(const _Float16* __restrict__ attnH, const float* __restrict__ V,
                    float* __restrict__ out) {
  const int b  = blockIdx.z;
  const int m0 = blockIdx.x * 64;
  const int n0 = blockIdx.y * 64;
  const int tid = threadIdx.x;
  const int w = tid >> 6, lane = tid & 63;

  __shared__ _Float16 aT[64][40];   // [m][k]
  __shared__ _Float16 vT[64][32];   // [n][k], swizzled

  const _Float16* aBase = attnH + (size_t)(b * NLQ + m0) * 2048;
  const float*    vBase = V + (size_t)b * NLK * NDV + n0;
  float*          oBase = out + (size_t)(b * NLQ + m0) * NDV + n0;

  const int ar = tid >> 2;               // 0..63
  const int ak = (tid & 3) * 8;          // 0,8,16,24
  const int vk = tid >> 4;               // 0..15
  const int vn = (tid & 15) * 4;         // 0..60
  const int vswz = ((vn >> 2) & 3) << 3;

  const int am  = w * 16 + (lane & 15);
  const int akf = (lane >> 4) * 8;
  const int bn  = lane & 15;
  const int bks = akf ^ (((bn >> 2) & 3) << 3);

  f32x4 acc0 = {}, acc1 = {}, acc2 = {}, acc3 = {};

  // prologue: prefetch tile 0 into registers
  float4 aReg = *(const float4*)&aBase[(size_t)ar * 2048 + ak];
  float4 vReg0 = *(const float4*)&vBase[(size_t)(vk) * NDV + vn];
  float4 vReg1 = *(const float4*)&vBase[(size_t)(16 + vk) * NDV + vn];

  for (int k0 = 0; k0 < NLK; k0 += 32) {
    __syncthreads();   // previous tile's LDS reads complete
    *(float4*)&aT[ar][ak] = aReg;
    {
      const int ks0 = vk ^ vswz;
      vT[vn + 0][ks0] = (_Float16)vReg0.x;
      vT[vn + 1][ks0] = (_Float16)vReg0.y;
      vT[vn + 2][ks0] = (_Float16)vReg0.z;
      vT[vn + 3][ks0] = (_Float16)vReg0.w;
      const int ks1 = (16 + vk) ^ vswz;
      vT[vn + 0][ks1] = (_Float16)vReg1.x;
      vT[vn + 1][ks1] = (_Float16)vReg1.y;
      vT[vn + 2][ks1] = (_Float16)vReg1.z;
      vT[vn + 3][ks1] = (_Float16)vReg1.w;
    }
    __syncthreads();

    // prefetch NEXT tile while current MFMAs run
    if (k0 + 32 < NLK) {
      aReg = *(const float4*)&aBase[(size_t)ar * 2048 + k0 + 32 + ak];
      vReg0 = *(const float4*)&vBase[(size_t)(k0 + 32 + vk) * NDV + vn];
      vReg1 = *(const float4*)&vBase[(size_t)(k0 + 48 + vk) * NDV + vn];
    }

    const f16x8 af = *(const f16x8*)&aT[am][akf];
    const f16x8 bf0 = *(const f16x8*)&vT[ 0 + bn][bks];
    const f16x8 bf1 = *(const f16x8*)&vT[16 + bn][bks];
    const f16x8 bf2 = *(const f16x8*)&vT[32 + bn][bks];
    const f16x8 bf3 = *(const f16x8*)&vT[48 + bn][bks];
    acc0 = __builtin_amdgcn_mfma_f32_16x16x32_f16(af, bf0, acc0, 0, 0, 0);
    acc1 = __builtin_amdgcn_mfma_f32_16x16x32_f16(af, bf1, acc1, 0, 0, 0);
    acc2 = __builtin_amdgcn_mfma_f32_16x16x32_f16(af, bf2, acc2, 0, 0, 0);
    acc3 = __builtin_amdgcn_mfma_f32_16x16x32_f16(af, bf3, acc3, 0, 0, 0);
  }

  const int orow = w * 16 + (lane >> 4) * 4;
  const int ocol = lane & 15;
#pragma unroll
  for (int r = 0; r < 4; ++r) {
    oBase[(size_t)(orow + r) * NDV + ocol +  0] = acc0[r];
    oBase[(size_t)(orow + r) * NDV + ocol + 16] = acc1[r];
    oBase[(size_t)(orow + r) * NDV + ocol + 32] = acc2[r];
    oBase[(size_t)(orow + r) * NDV + ocol + 48] = acc3[r];
  }
}

// ---------------------------------------------------------------------------
extern "C" void kernel_launch(void* const* d_in, const int* in_sizes, int n_in,
                              void* d_out, int out_size, void* d_ws, size_t ws_size,
                              hipStream_t stream) {
  const float* Q    = (const float*)d_in[0];
  const float* Kin  = (const float*)d_in[1];
  const float* V    = (const float*)d_in[2];
  const int*   vlen = (const int*)d_in[3];
  const float* Wq   = (const float*)d_in[4];
  const float* Wk   = (const float*)d_in[5];
  const float* wv   = (const float*)d_in[6];
  float* out = (float*)d_out;

  float* qp  = (float*)d_ws;                    // Eq: 2048*128 row-major
  float* ekT = qp + NBATCH * NLQ * NH;          // EkT: 8*128*1024
  float* sc  = ekT + NBATCH * NH * NLK;         // scores fp32 -> attn fp16 (in place)

  hipLaunchKernelGGL(proj_kernel, dim3(160, 2), dim3(256), 0, stream,
                     Q, Kin, Wq, Wk, qp, ekT);
  hipLaunchKernelGGL(scores_kernel, dim3(2, 64, NBATCH), dim3(256), 0, stream,
                     qp, ekT, wv, sc);
  hipLaunchKernelGGL(softmax_kernel, dim3(NBATCH * NLQ / 4), dim3(256), 0, stream,
                     sc, vlen);
  hipLaunchKernelGGL(pv_mfma_kernel, dim3(NLQ / 64, NDV / 64, NBATCH), dim3(256), 0, stream,
                     (const _Float16*)sc, V, out);
}

// Round 9
// 89.298 us; speedup vs baseline: 2.7433x; 1.0278x over previous
//
#include <hip/hip_runtime.h>

// Problem constants
#define NBATCH 8
#define NLQ    256
#define NLK    1024
#define NDQ    512
#define NDV    512
#define NH     128
#define NEGV   -1000000.0f
#define TANH_SCALE 2.8853900817779268f   // 2*log2(e)
#define LOG2E      1.4426950408889634f

using f16x8 = __attribute__((ext_vector_type(8))) _Float16;
using f16x4 = __attribute__((ext_vector_type(4))) _Float16;
using f32x4 = __attribute__((ext_vector_type(4))) float;

__device__ __forceinline__ float fast_exp2(float x) {
#if __has_builtin(__builtin_amdgcn_exp2f)
  return __builtin_amdgcn_exp2f(x);
#else
  return exp2f(x);
#endif
}
__device__ __forceinline__ float fast_rcp(float x) {
#if __has_builtin(__builtin_amdgcn_rcpf)
  return __builtin_amdgcn_rcpf(x);
#else
  return 1.0f / x;
#endif
}

// ---------------------------------------------------------------------------
// Prep: WT fp16 [2][128][512]; WT[s][n][k] = W_s[k][n]. 256 KB, L2-resident.
// Coalesced reads (n inner), scattered 2B writes (tiny one-off cost).
// ---------------------------------------------------------------------------
__global__ __launch_bounds__(256)
void prep_wT_kernel(const float* __restrict__ Wq, const float* __restrict__ Wk,
                    _Float16* __restrict__ wT) {
  const int idx = blockIdx.x * 256 + threadIdx.x;   // 0 .. 2*512*128-1
  const int n = idx & 127;
  const int k = (idx >> 7) & 511;
  const int s = idx >> 16;
  const float* W = s ? Wk : Wq;
  wT[((size_t)(s * NH + n)) * NDQ + k] = (_Float16)W[k * NH + n];
}

// ---------------------------------------------------------------------------
// Projections via fp16 MFMA, LDS-FREE, barrier-free.
// Wave = 16 rows x 32 cols (2 frags of 16x16), block = 4 waves (64 rows).
// Grid (160, 4): bx<32 -> Q (M=2048), else K (M=8192); by = n-quarter.
// A-frag: per-lane 2x float4 from A[row][k], row=lane&15, k=8*(lane>>4)+j,
// cvt fp32->fp16. B-frag: one f16x8 from WT[n][k] (L2). Accum fp32.
// Epilogue: exp2(acc*2log2e); Q -> Eq row-major, K -> EkT[b][h][key].
// ---------------------------------------------------------------------------
__global__ __launch_bounds__(256)
void proj_mfma_kernel(const float* __restrict__ Q, const float* __restrict__ Kin,
                      const _Float16* __restrict__ wT,
                      float* __restrict__ qp, float* __restrict__ ekT) {
  const int bx = blockIdx.x;
  const int nq = blockIdx.y;          // n-quarter: cols nq*32 .. nq*32+31
  const bool isQ = (bx < 32);
  const float* A = isQ ? Q : Kin;
  const int m0 = (isQ ? bx : bx - 32) * 64;
  const int sIdx = isQ ? 0 : 1;

  const int w = threadIdx.x >> 6, lane = threadIdx.x & 63;
  const int mrow = m0 + w * 16 + (lane & 15);
  const int kseg = (lane >> 4) * 8;

  const float* aBase = A + (size_t)mrow * NDQ + kseg;
  const _Float16* wt0 = wT + ((size_t)(sIdx * NH + nq * 32 +      (lane & 15))) * NDQ + kseg;
  const _Float16* wt1 = wT + ((size_t)(sIdx * NH + nq * 32 + 16 + (lane & 15))) * NDQ + kseg;

  f32x4 acc0 = {}, acc1 = {};
#pragma unroll 4
  for (int k0 = 0; k0 < NDQ; k0 += 32) {
    const float4 a0 = *(const float4*)&aBase[k0];
    const float4 a1 = *(const float4*)&aBase[k0 + 4];
    f16x8 af;
    af[0] = (_Float16)a0.x; af[1] = (_Float16)a0.y;
    af[2] = (_Float16)a0.z; af[3] = (_Float16)a0.w;
    af[4] = (_Float16)a1.x; af[5] = (_Float16)a1.y;
    af[6] = (_Float16)a1.z; af[7] = (_Float16)a1.w;
    const f16x8 b0 = *(const f16x8*)&wt0[k0];
    const f16x8 b1 = *(const f16x8*)&wt1[k0];
    acc0 = __builtin_amdgcn_mfma_f32_16x16x32_f16(af, b0, acc0, 0, 0, 0);
    acc1 = __builtin_amdgcn_mfma_f32_16x16x32_f16(af, b1, acc1, 0, 0, 0);
  }

  const int orow = m0 + w * 16 + (lane >> 4) * 4;   // + r
  const int col0 = nq * 32 + (lane & 15);           // frag0 col; frag1 = +16
  if (isQ) {
#pragma unroll
    for (int r = 0; r < 4; ++r) {
      qp[(size_t)(orow + r) * NH + col0]      = fast_exp2(acc0[r] * TANH_SCALE);
      qp[(size_t)(orow + r) * NH + col0 + 16] = fast_exp2(acc1[r] * TANH_SCALE);
    }
  } else {
#pragma unroll
    for (int r = 0; r < 4; ++r) {
      const int grow = orow + r;
      const int b = grow >> 10, key = grow & 1023;
      ekT[((size_t)(b * NH) + col0)      * NLK + key] = fast_exp2(acc0[r] * TANH_SCALE);
      ekT[((size_t)(b * NH) + col0 + 16) * NLK + key] = fast_exp2(acc1[r] * TANH_SCALE);
    }
  }
}

// ---------------------------------------------------------------------------
// Scores: COALESCED k. EkT[b][h][key]: lane owns keys key0=seg*128+2*lane
// (float2 loads -> consecutive lanes, consecutive addresses). Eq rows + w_v
// via wave-uniform addresses -> scalar loads. Per wave: 128 keys x 4 q rows.
//   score = Wsum - 2*sum_h w*rcp(1 + Eq*Ek); Wsum cancels in softmax.
// ---------------------------------------------------------------------------
__global__ __launch_bounds__(256)
void scores_kernel(const float* __restrict__ qp, const float* __restrict__ ekT,
                   const float* __restrict__ wv, float* __restrict__ sc) {
  const int w = threadIdx.x >> 6;
  const int lane = threadIdx.x & 63;
  const int seg = blockIdx.x * 4 + w;   // key segment (128 keys)
  const int qg  = blockIdx.y;           // q group (4 rows)
  const int b   = blockIdx.z;
  const int key0 = seg * 128 + lane * 2;

  const float* kcol  = &ekT[(size_t)b * NH * NLK + key0];       // + h*NLK
  const float* qbase = &qp[(size_t)(b * NLQ + qg * 4) * NH];

  float2 acc[4] = {};
#pragma unroll 8
  for (int g = 0; g < 32; ++g) {
    const float4 w4 = *(const float4*)&wv[g * 4];               // uniform
    float4 q4[4];
#pragma unroll
    for (int qi = 0; qi < 4; ++qi)
      q4[qi] = *(const float4*)&qbase[qi * NH + g * 4];         // uniform
#pragma unroll
    for (int hh = 0; hh < 4; ++hh) {
      const float2 kv = *(const float2*)&kcol[(size_t)(g * 4 + hh) * NLK];
      const float wl = (hh == 0) ? w4.x : (hh == 1) ? w4.y : (hh == 2) ? w4.z : w4.w;
#pragma unroll
      for (int qi = 0; qi < 4; ++qi) {
        const float qs = (hh == 0) ? q4[qi].x : (hh == 1) ? q4[qi].y
                       : (hh == 2) ? q4[qi].z : q4[qi].w;
        acc[qi].x = fmaf(wl, fast_rcp(fmaf(qs, kv.x, 1.0f)), acc[qi].x);
        acc[qi].y = fmaf(wl, fast_rcp(fmaf(qs, kv.y, 1.0f)), acc[qi].y);
      }
    }
  }

#pragma unroll
  for (int qi = 0; qi < 4; ++qi) {
    float2 o;
    o.x = -2.0f * acc[qi].x;
    o.y = -2.0f * acc[qi].y;
    *(float2*)&sc[(size_t)(b * NLQ + qg * 4 + qi) * NLK + key0] = o;
  }
}

// ---------------------------------------------------------------------------
// Masked softmax over keys; reads fp32 scores, writes fp16 attn IN PLACE
// (row r's halfs overlay row r's own floats; reads precede stores -> safe).
// ---------------------------------------------------------------------------
__global__ __launch_bounds__(256)
void softmax_kernel(float* __restrict__ sc, const int* __restrict__ vlen) {
  const int row = blockIdx.x * 4 + (threadIdx.x >> 6);  // 0..2047
  const int lane = threadIdx.x & 63;
  const int VL = vlen[row >> 8];
  float* base = &sc[(size_t)row * NLK];

  float s[16];
#pragma unroll
  for (int g = 0; g < 4; ++g) {
    const int k0 = (g * 64 + lane) * 4;
    const float4 v = *(const float4*)&base[k0];
    s[g * 4 + 0] = (k0 + 0 < VL) ? v.x : NEGV;
    s[g * 4 + 1] = (k0 + 1 < VL) ? v.y : NEGV;
    s[g * 4 + 2] = (k0 + 2 < VL) ? v.z : NEGV;
    s[g * 4 + 3] = (k0 + 3 < VL) ? v.w : NEGV;
  }

  float m = s[0];
#pragma unroll
  for (int t = 1; t < 16; ++t) m = fmaxf(m, s[t]);
#pragma unroll
  for (int off = 32; off > 0; off >>= 1) m = fmaxf(m, __shfl_xor(m, off));

  float p[16];
  float sum = 0.0f;
#pragma unroll
  for (int t = 0; t < 16; ++t) {
    p[t] = fast_exp2((s[t] - m) * LOG2E);
    sum += p[t];
  }
#pragma unroll
  for (int off = 32; off > 0; off >>= 1) sum += __shfl_xor(sum, off);
  const float inv = fast_rcp(sum);

  _Float16* hbase = (_Float16*)base;
#pragma unroll
  for (int g = 0; g < 4; ++g) {
    const int k0 = (g * 64 + lane) * 4;
    f16x4 h;
    h[0] = (_Float16)(p[g * 4 + 0] * inv);
    h[1] = (_Float16)(p[g * 4 + 1] * inv);
    h[2] = (_Float16)(p[g * 4 + 2] * inv);
    h[3] = (_Float16)(p[g * 4 + 3] * inv);
    *(f16x4*)&hbase[k0] = h;
  }
}

// ---------------------------------------------------------------------------
// PV via fp16 MFMA: out[b] = attn[b] (256x1024 fp16, row stride 2048) @ V[b].
// Block 256 thr = 4 waves; tile M64 x N64, K-step 32, register prefetch.
// ---------------------------------------------------------------------------
__global__ __launch_bounds__(256)
void pv_mfma_kernel(const _Float16* __restrict__ attnH, const float* __restrict__ V,
                    float* __restrict__ out) {
  const int b  = blockIdx.z;
  const int m0 = blockIdx.x * 64;
  const int n0 = blockIdx.y * 64;
  const int tid = threadIdx.x;
  const int w = tid >> 6, lane = tid & 63;

  __shared__ _Float16 aT[64][40];   // [m][k]
  __shared__ _Float16 vT[64][32];   // [n][k], swizzled

  const _Float16* aBase = attnH + (size_t)(b * NLQ + m0) * 2048;
  const float*    vBase = V + (size_t)b * NLK * NDV + n0;
  float*          oBase = out + (size_t)(b * NLQ + m0) * NDV + n0;

  const int ar = tid >> 2;               // 0..63
  const int ak = (tid & 3) * 8;          // 0,8,16,24
  const int vk = tid >> 4;               // 0..15
  const int vn = (tid & 15) * 4;         // 0..60
  const int vswz = ((vn >> 2) & 3) << 3;

  const int am  = w * 16 + (lane & 15);
  const int akf = (lane >> 4) * 8;
  const int bn  = lane & 15;
  const int bks = akf ^ (((bn >> 2) & 3) << 3);

  f32x4 acc0 = {}, acc1 = {}, acc2 = {}, acc3 = {};

  // prologue: prefetch tile 0 into registers
  float4 aReg = *(const float4*)&aBase[(size_t)ar * 2048 + ak];
  float4 vReg0 = *(const float4*)&vBase[(size_t)(vk) * NDV + vn];
  float4 vReg1 = *(const float4*)&vBase[(size_t)(16 + vk) * NDV + vn];

  for (int k0 = 0; k0 < NLK; k0 += 32) {
    __syncthreads();   // previous tile's LDS reads complete
    *(float4*)&aT[ar][ak] = aReg;
    {
      const int ks0 = vk ^ vswz;
      vT[vn + 0][ks0] = (_Float16)vReg0.x;
      vT[vn + 1][ks0] = (_Float16)vReg0.y;
      vT[vn + 2][ks0] = (_Float16)vReg0.z;
      vT[vn + 3][ks0] = (_Float16)vReg0.w;
      const int ks1 = (16 + vk) ^ vswz;
      vT[vn + 0][ks1] = (_Float16)vReg1.x;
      vT[vn + 1][ks1] = (_Float16)vReg1.y;
      vT[vn + 2][ks1] = (_Float16)vReg1.z;
      vT[vn + 3][ks1] = (_Float16)vReg1.w;
    }
    __syncthreads();

    // prefetch NEXT tile while current MFMAs run
    if (k0 + 32 < NLK) {
      aReg = *(const float4*)&aBase[(size_t)ar * 2048 + k0 + 32 + ak];
      vReg0 = *(const float4*)&vBase[(size_t)(k0 + 32 + vk) * NDV + vn];
      vReg1 = *(const float4*)&vBase[(size_t)(k0 + 48 + vk) * NDV + vn];
    }

    const f16x8 af = *(const f16x8*)&aT[am][akf];
    const f16x8 bf0 = *(const f16x8*)&vT[ 0 + bn][bks];
    const f16x8 bf1 = *(const f16x8*)&vT[16 + bn][bks];
    const f16x8 bf2 = *(const f16x8*)&vT[32 + bn][bks];
    const f16x8 bf3 = *(const f16x8*)&vT[48 + bn][bks];
    acc0 = __builtin_amdgcn_mfma_f32_16x16x32_f16(af, bf0, acc0, 0, 0, 0);
    acc1 = __builtin_amdgcn_mfma_f32_16x16x32_f16(af, bf1, acc1, 0, 0, 0);
    acc2 = __builtin_amdgcn_mfma_f32_16x16x32_f16(af, bf2, acc2, 0, 0, 0);
    acc3 = __builtin_amdgcn_mfma_f32_16x16x32_f16(af, bf3, acc3, 0, 0, 0);
  }

  const int orow = w * 16 + (lane >> 4) * 4;
  const int ocol = lane & 15;
#pragma unroll
  for (int r = 0; r < 4; ++r) {
    oBase[(size_t)(orow + r) * NDV + ocol +  0] = acc0[r];
    oBase[(size_t)(orow + r) * NDV + ocol + 16] = acc1[r];
    oBase[(size_t)(orow + r) * NDV + ocol + 32] = acc2[r];
    oBase[(size_t)(orow + r) * NDV + ocol + 48] = acc3[r];
  }
}

// ---------------------------------------------------------------------------
extern "C" void kernel_launch(void* const* d_in, const int* in_sizes, int n_in,
                              void* d_out, int out_size, void* d_ws, size_t ws_size,
                              hipStream_t stream) {
  const float* Q    = (const float*)d_in[0];
  const float* Kin  = (const float*)d_in[1];
  const float* V    = (const float*)d_in[2];
  const int*   vlen = (const int*)d_in[3];
  const float* Wq   = (const float*)d_in[4];
  const float* Wk   = (const float*)d_in[5];
  const float* wv   = (const float*)d_in[6];
  float* out = (float*)d_out;

  float* qp  = (float*)d_ws;                    // Eq: 2048*128 row-major
  float* ekT = qp + NBATCH * NLQ * NH;          // EkT: 8*128*1024
  float* sc  = ekT + NBATCH * NH * NLK;         // scores fp32 -> attn fp16 (in place)
  _Float16* wT = (_Float16*)(sc + (size_t)NBATCH * NLQ * NLK);  // 2*128*512 fp16

  hipLaunchKernelGGL(prep_wT_kernel, dim3(2 * NDQ * NH / 256), dim3(256), 0, stream,
                     Wq, Wk, wT);
  hipLaunchKernelGGL(proj_mfma_kernel, dim3(160, 4), dim3(256), 0, stream,
                     Q, Kin, wT, qp, ekT);
  hipLaunchKernelGGL(scores_kernel, dim3(2, 64, NBATCH), dim3(256), 0, stream,
                     qp, ekT, wv, sc);
  hipLaunchKernelGGL(softmax_kernel, dim3(NBATCH * NLQ / 4), dim3(256), 0, stream,
                     sc, vlen);
  hipLaunchKernelGGL(pv_mfma_kernel, dim3(NLQ / 64, NDV / 64, NBATCH), dim3(256), 0, stream,
                     (const _Float16*)sc, V, out);
}